// Round 2
// baseline (3091.652 us; speedup 1.0000x reference)
//
#include <hip/hip_runtime.h>
#include <hip/hip_bf16.h>
#include <math.h>

#define BS 4
#define CIN 256
#define HF 56
#define WF 120
#define CF 64
#define DD 48
#define HW (HF*WF)          // 6720
#define BEVX 128
#define BEVY 128
#define NCELL (BEVX*BEVY)   // 16384
#define NPTS (DD*HW)        // 322560

// ---------------- conv 5x5 (pad 2) + affine + relu ----------------
// grid: (4, 7, BS*4)  block: 256.  Tile 8h x 32w, 16 out-channels per block.
#define TH 8
#define TW 32

__global__ __launch_bounds__(256) void conv5_kernel(
    const float* __restrict__ in, const float* __restrict__ wgt,
    const float* __restrict__ bias, const float* __restrict__ gamma,
    const float* __restrict__ beta, float* __restrict__ out, int layout)
{
    __shared__ float tile[4 * 12 * 36];   // 4 ci x (TH+4) x (TW+4)
    const int tid = threadIdx.x;
    const int tw0 = blockIdx.x * TW;
    const int th0 = blockIdx.y * TH;
    const int bz  = blockIdx.z;
    const int b   = bz >> 2;
    const int nc  = (bz & 3) * 16;
    const int lw  = tid & 31;
    const int lh  = tid >> 5;
    const int ow  = tw0 + lw;
    const int oh  = th0 + lh;

    const float* inb = in + (size_t)b * CIN * HW;

    float acc[16];
#pragma unroll
    for (int n = 0; n < 16; ++n) acc[n] = 0.f;

    for (int ci0 = 0; ci0 < CIN; ci0 += 4) {
        // stage 4 input channels of the (TH+4)x(TW+4) halo tile
        for (int idx = tid; idx < 4 * 12 * 36; idx += 256) {
            int c   = idx / 432;
            int rem = idx - c * 432;
            int r   = rem / 36;
            int cc  = rem - r * 36;
            int gh  = th0 + r - 2;
            int gw  = tw0 + cc - 2;
            float val = 0.f;
            if ((unsigned)gh < (unsigned)HF && (unsigned)gw < (unsigned)WF)
                val = inb[(size_t)(ci0 + c) * HW + gh * WF + gw];
            tile[idx] = val;
        }
        __syncthreads();

#pragma unroll
        for (int c = 0; c < 4; ++c) {
            float v[25];
#pragma unroll
            for (int kh = 0; kh < 5; ++kh)
#pragma unroll
                for (int kw = 0; kw < 5; ++kw)
                    v[kh * 5 + kw] = tile[c * 432 + (lh + kh) * 36 + (lw + kw)];

            const float* wp = wgt + ((size_t)nc * CIN + (ci0 + c)) * 25;
#pragma unroll
            for (int n = 0; n < 16; ++n) {
                const float* w = wp + (size_t)n * CIN * 25;   // uniform -> scalar loads
                float a = acc[n];
#pragma unroll
                for (int k = 0; k < 25; ++k) a = fmaf(v[k], w[k], a);
                acc[n] = a;
            }
        }
        __syncthreads();
    }

    if (ow < WF) {
#pragma unroll
        for (int n = 0; n < 16; ++n) {
            int ch = nc + n;
            float r = gamma[ch] * (acc[n] + bias[ch]) + beta[ch];
            r = fmaxf(r, 0.f);
            if (layout == 0)
                out[((size_t)b * HW + oh * WF + ow) * CF + ch] = r;      // (b,h,w,c)
            else
                out[((size_t)b * CF + ch) * HW + oh * WF + ow] = r;      // (b,c,h,w)
        }
    }
}

// ---------------- depth head: 1x1 conv (64->48) + softmax over d ----------------
__global__ __launch_bounds__(256) void depth_kernel(
    const float* __restrict__ dec, const float* __restrict__ dw,
    const float* __restrict__ db, float* __restrict__ depth)
{
    int pid = blockIdx.x * 256 + threadIdx.x;   // 0..26879
    int b  = pid / HW;
    int hw = pid - b * HW;
    const float* dp = dec + (size_t)b * CF * HW + hw;

    float acc[DD];
#pragma unroll
    for (int d = 0; d < DD; ++d) acc[d] = db[d];

    for (int c = 0; c < CF; ++c) {
        float v = dp[(size_t)c * HW];
#pragma unroll
        for (int d = 0; d < DD; ++d) acc[d] = fmaf(v, dw[d * CF + c], acc[d]);
    }

    float m = acc[0];
#pragma unroll
    for (int d = 1; d < DD; ++d) m = fmaxf(m, acc[d]);
    float s = 0.f;
#pragma unroll
    for (int d = 0; d < DD; ++d) { acc[d] = expf(acc[d] - m); s += acc[d]; }
    float inv = 1.0f / s;

    float* op = depth + (size_t)b * DD * HW + hw;
#pragma unroll
    for (int d = 0; d < DD; ++d) op[(size_t)d * HW] = acc[d] * inv;
}

// ---------------- geometry: per (d,h,w) point -> BEV cell (+count) ----------------
// Bit-replicates the numpy fp32 pipeline:
//  * np.linalg.inv (LAPACK sgetrf+sgetri -> strti2 on the upper-triangular K)
//  * pix @ Kinv.T and cam @ R.T via BLAS sgemm: FMA accumulation, ascending k
//  * separate broadcast add of t, IEEE fp32 division by 0.6f, two separate adds
__global__ __launch_bounds__(256) void geom_kernel(
    const float* __restrict__ intr, const float* __restrict__ extr,
    int* __restrict__ cells, int* __restrict__ counts)
{
    int idx = blockIdx.x * 256 + threadIdx.x;   // < NPTS
    int d  = idx / HW;
    int hw = idx - d * HW;
    int h  = hw / WF;
    int w  = hw - h * WF;

    float k00 = intr[0], k01 = intr[1], k02 = intr[2];
    float k11 = intr[4], k12 = intr[5];
    float k22 = intr[8];

    // LAPACK strti2 replica (K is upper-triangular, getrf is a no-op, L = I)
    float A00 = __fdiv_rn(1.0f, k00);
    float A11 = __fdiv_rn(1.0f, k11);
    float A01 = __fmul_rn(__fmul_rn(k01, A00), -A11);        // strmv then sscal
    float A22 = __fdiv_rn(1.0f, k22);
    float x0  = __fmul_rn(k02, A00);                         // strmv col 3, j=1
    x0        = __fadd_rn(x0, __fmul_rn(k12, A01));          // strmv col 3, j=2 (adds -0 here)
    float x1  = __fmul_rn(k12, A11);
    float A02 = __fmul_rn(x0, -A22);                         // sscal
    float A12 = __fmul_rn(x1, -A22);

    float i00 = A00, i01 = A01, i02 = A02;
    float i10 = 0.f, i11 = A11, i12 = A12;
    float i20 = 0.f, i21 = 0.f, i22 = A22;

    float u   = (w + 0.5f) * 8.0f;          // exact
    float v   = (h + 0.5f) * 8.0f;          // exact
    float dsv = 2.0f + (float)d;            // exact
    float px  = __fmul_rn(u, dsv);          // exact (<2^24 integers)
    float py  = __fmul_rn(v, dsv);
    float pz  = dsv;

    // cam = pix @ Kinv.T : sgemm FMA chain, k ascending
    float cam0 = fmaf(pz, i02, fmaf(py, i01, fmaf(px, i00, 0.0f)));
    float cam1 = fmaf(pz, i12, fmaf(py, i11, fmaf(px, i10, 0.0f)));
    float cam2 = fmaf(pz, i22, fmaf(py, i21, fmaf(px, i20, 0.0f)));

    float r00 = extr[0], r01 = extr[1], r02 = extr[2],  t0 = extr[3];
    float r10 = extr[4], r11 = extr[5], r12 = extr[6],  t1 = extr[7];

    // mm = cam @ R.T (FMA chain), then ego = mm + t (separate broadcast add)
    float mm0 = fmaf(cam2, r02, fmaf(cam1, r01, fmaf(cam0, r00, 0.0f)));
    float mm1 = fmaf(cam2, r12, fmaf(cam1, r11, fmaf(cam0, r10, 0.0f)));
    float e0  = __fadd_rn(mm0, t0);
    float e1  = __fadd_rn(mm1, t1);

    float ixf = floorf(__fadd_rn(__fadd_rn(__fdiv_rn(e0, 0.6f), 32.0f), 64.0f));
    float iyf = floorf(__fadd_rn(__fdiv_rn(e1, 0.6f), 64.0f));
    int ix = (int)ixf;
    int iy = (int)iyf;

    bool valid = (ix >= 0) && (ix < BEVX) && (iy >= 0) && (iy < BEVY);
    int cell = valid ? iy * BEVX + ix : -1;
    cells[idx] = cell;
    if (valid) atomicAdd(&counts[cell], 1);
}

// ---------------- exclusive scan of cell counts ----------------
__global__ __launch_bounds__(256) void scan_kernel(
    const int* __restrict__ counts, int* __restrict__ offsets, int* __restrict__ cursor)
{
    __shared__ int sums[256];
    int t = threadIdx.x;
    int base = t * 64;
    int s = 0;
    for (int i = 0; i < 64; ++i) s += counts[base + i];
    sums[t] = s;
    __syncthreads();
    if (t == 0) {
        int run = 0;
        for (int i = 0; i < 256; ++i) { int v = sums[i]; sums[i] = run; run += v; }
        offsets[NCELL] = run;
    }
    __syncthreads();
    int run = sums[t];
    for (int i = 0; i < 64; ++i) {
        offsets[base + i] = run;
        cursor[base + i]  = run;
        run += counts[base + i];
    }
}

// ---------------- fill point lists ----------------
__global__ __launch_bounds__(256) void fill_kernel(
    const int* __restrict__ cells, int* __restrict__ cursor, int* __restrict__ plist)
{
    int idx = blockIdx.x * 256 + threadIdx.x;
    int c = cells[idx];
    if (c >= 0) {
        int pos = atomicAdd(&cursor[c], 1);
        int d  = idx / HW;
        int hw = idx - d * HW;
        plist[pos] = (d << 16) | hw;
    }
}

// ---------------- gather: one wave per (cell, batch) ----------------
__global__ __launch_bounds__(64) void gather_kernel(
    const float* __restrict__ xT, const float* __restrict__ depth,
    const int* __restrict__ offsets, const int* __restrict__ plist,
    float* __restrict__ out)
{
    int cell = blockIdx.x;
    int b    = blockIdx.y;
    int lane = threadIdx.x;
    int s = offsets[cell];
    int e = offsets[cell + 1];
    const float* xb = xT + (size_t)b * HW * CF;
    const float* dp = depth + (size_t)b * DD * HW;
    float acc = 0.f;
    for (int i = s; i < e; ++i) {
        int p  = plist[i];
        int hw = p & 0xFFFF;
        int d  = p >> 16;
        acc = fmaf(dp[d * HW + hw], xb[(size_t)hw * CF + lane], acc);
    }
    out[((size_t)b * CF + lane) * NCELL + cell] = acc;
}

// ---------------- launch ----------------
extern "C" void kernel_launch(void* const* d_in, const int* in_sizes, int n_in,
                              void* d_out, int out_size, void* d_ws, size_t ws_size,
                              hipStream_t stream)
{
    const float* state   = (const float*)d_in[0];
    const float* intr    = (const float*)d_in[1];
    const float* extr    = (const float*)d_in[2];
    const float* feat_w  = (const float*)d_in[3];
    const float* feat_b  = (const float*)d_in[4];
    const float* feat_g  = (const float*)d_in[5];
    const float* feat_bt = (const float*)d_in[6];
    const float* dec_w   = (const float*)d_in[7];
    const float* dec_b   = (const float*)d_in[8];
    const float* dec_g   = (const float*)d_in[9];
    const float* dec_bt  = (const float*)d_in[10];
    const float* depth_w = (const float*)d_in[11];
    const float* depth_b = (const float*)d_in[12];
    float* out = (float*)d_out;

    // workspace layout
    float* xT    = (float*)d_ws;                 // BS*HW*CF
    float* decC  = xT   + (size_t)BS * HW * CF;  // BS*CF*HW
    float* depth = decC + (size_t)BS * CF * HW;  // BS*DD*HW
    int*   cells = (int*)(depth + (size_t)BS * DD * HW);  // NPTS
    int*   plist = cells + NPTS;                 // NPTS
    int*   counts  = plist + NPTS;               // NCELL
    int*   offsets = counts + NCELL;             // NCELL+1
    int*   cursor  = offsets + NCELL + 1;        // NCELL

    hipMemsetAsync(counts, 0, NCELL * sizeof(int), stream);

    dim3 cgrid(4, 7, BS * 4);
    conv5_kernel<<<cgrid, 256, 0, stream>>>(state, feat_w, feat_b, feat_g, feat_bt, xT, 0);
    conv5_kernel<<<cgrid, 256, 0, stream>>>(state, dec_w, dec_b, dec_g, dec_bt, decC, 1);

    depth_kernel<<<(BS * HW) / 256, 256, 0, stream>>>(decC, depth_w, depth_b, depth);

    geom_kernel<<<NPTS / 256, 256, 0, stream>>>(intr, extr, cells, counts);
    scan_kernel<<<1, 256, 0, stream>>>(counts, offsets, cursor);
    fill_kernel<<<NPTS / 256, 256, 0, stream>>>(cells, cursor, plist);

    dim3 ggrid(NCELL, BS);
    gather_kernel<<<ggrid, 64, 0, stream>>>(xT, depth, offsets, plist, out);
}

// Round 4
// 627.085 us; speedup vs baseline: 4.9302x; 4.9302x over previous
//
#include <hip/hip_runtime.h>
#include <hip/hip_bf16.h>
#include <math.h>

#define BS 4
#define CIN 256
#define HF 56
#define WF 120
#define CF 64
#define DD 48
#define HW (HF*WF)          // 6720
#define BEVX 128
#define BEVY 128
#define NCELL (BEVX*BEVY)   // 16384
#define NPTS (DD*HW)        // 322560

#define PH 60               // padded rows
#define PW 124              // padded cols

typedef short s16x8 __attribute__((ext_vector_type(8)));
typedef float f32x4 __attribute__((ext_vector_type(4)));

__device__ __forceinline__ unsigned short f2bf(float f) {
    unsigned int u = __float_as_uint(f);
    unsigned int r = (u + 0x7FFFu + ((u >> 16) & 1u)) >> 16;
    return (unsigned short)r;
}

// ---------------- pad + transpose: state (b,ci,h,w) f32 -> P (b,h+2,w+2,ci) bf16 ----------------
__global__ __launch_bounds__(128) void pad_transpose_kernel(
    const float* __restrict__ state, unsigned short* __restrict__ P)
{
    int w = threadIdx.x;
    int h = blockIdx.x;
    int b = blockIdx.y;
    if (w >= WF) return;
    const float* src = state + (((size_t)b * CIN) * HF + h) * WF + w;
    unsigned short* dst = P + (((size_t)b * PH + (h + 2)) * PW + (w + 2)) * CIN;
    for (int c0 = 0; c0 < CIN; c0 += 8) {
        unsigned short tmp[8];
#pragma unroll
        for (int j = 0; j < 8; ++j)
            tmp[j] = f2bf(src[(size_t)(c0 + j) * HW]);
        *(int4*)(dst + c0) = *(const int4*)tmp;
    }
}

// ---------------- weight pack: (feat|dec) (64,256,5,5) f32 -> Wf bf16 B-fragments ----------------
// Wf entry e = ((p*8+kc)*8 + nf)*64 + lane : 8 bf16 = W[n=nf*16+(lane&15)][ci=kc*32+(lane>>4)*8 + j][p]
__global__ __launch_bounds__(256) void pack_w_kernel(
    const float* __restrict__ fw, const float* __restrict__ dw,
    unsigned short* __restrict__ Wf)
{
    int tid = blockIdx.x * 256 + threadIdx.x;
    if (tid >= 25 * 8 * 8 * 64) return;
    int lane = tid & 63;
    int nf = (tid >> 6) & 7;
    int kc = (tid >> 9) & 7;
    int p  = tid >> 12;
    int n   = nf * 16 + (lane & 15);
    int ci0 = kc * 32 + (lane >> 4) * 8;
    const float* src = (n < 64) ? fw + (size_t)n * CIN * 25
                                : dw + (size_t)(n - 64) * CIN * 25;
    unsigned short v[8];
#pragma unroll
    for (int j = 0; j < 8; ++j)
        v[j] = f2bf(src[(size_t)(ci0 + j) * 25 + p]);
    *(int4*)(Wf + (size_t)tid * 8) = *(const int4*)v;
}

__global__ __launch_bounds__(128) void pack_aff_kernel(
    const float* __restrict__ fb, const float* __restrict__ fg, const float* __restrict__ fbt,
    const float* __restrict__ db, const float* __restrict__ dg, const float* __restrict__ dbt,
    float2* __restrict__ aff)
{
    int n = threadIdx.x;
    if (n >= 128) return;
    float g, bi, bt;
    if (n < 64) { g = fg[n]; bi = fb[n]; bt = fbt[n]; }
    else        { g = dg[n - 64]; bi = db[n - 64]; bt = dbt[n - 64]; }
    aff[n] = make_float2(g, g * bi + bt);
}

// ---------------- fused conv (feat+dec) via MFMA implicit GEMM ----------------
// grid (15,7,4), 512 threads (8 waves). Block: 64 pixels (8x8) x 128 out-ch.
// Wave (wm,wn) = 32 pixels x 32 out-ch. K = 25 taps x 256 ch, stepped 32 ch at a time.
__global__ __launch_bounds__(512) void conv_mfma_kernel(
    const unsigned short* __restrict__ P, const unsigned short* __restrict__ Wf,
    const float2* __restrict__ aff, float* __restrict__ xT, float* __restrict__ decC)
{
    __shared__ __align__(16) unsigned short lds[2][144 * 32];  // [buf][pix][32ch] bf16, 9216 B each

    const int tid  = threadIdx.x;
    const int lane = tid & 63;
    const int wid  = tid >> 6;
    const int wm   = wid >> 2;   // 0..1
    const int wn   = wid & 3;    // 0..3
    const int b  = blockIdx.z;
    const int h0 = blockIdx.y * 8;
    const int w0 = blockIdx.x * 8;

    const unsigned short* Pb = P + (((size_t)b * PH + h0) * PW + w0) * CIN;

    // staging: 576 chunks of 16B (144 pix x 4 slots). chunk c: pix=c>>2, slot=c&3.
    // LDS slot swizzle s' = slot ^ ((pix>>1)&3)  (content kg == global slot)
    const int c0 = tid;
    const int pix0 = c0 >> 2, slot0 = c0 & 3;
    const size_t g0 = ((size_t)(pix0 / 12) * PW + (pix0 % 12)) * CIN + slot0 * 8;
    const int l0 = pix0 * 32 + (slot0 ^ ((pix0 >> 1) & 3)) * 8;   // ushort units
    const int c1 = 512 + tid;
    const int pix1 = c1 >> 2, slot1 = c1 & 3;
    const size_t g1 = ((size_t)(pix1 / 12) * PW + (pix1 % 12)) * CIN + slot1 * 8;
    const int l1 = pix1 * 32 + (slot1 ^ ((pix1 >> 1) & 3)) * 8;
    const bool has2 = (tid < 64);

    f32x4 acc[2][2];
#pragma unroll
    for (int i = 0; i < 2; ++i)
#pragma unroll
        for (int j = 0; j < 2; ++j)
            acc[i][j] = (f32x4){0.f, 0.f, 0.f, 0.f};

    // per-lane A coords
    const int kg = lane >> 4;
    const int m0 = wm * 32 + (lane & 15);
    const int m1 = m0 + 16;
    const int pb0 = ((m0 >> 3)) * 12 + (m0 & 7);   // halo pixel base (add dh*12+dw)
    const int pb1 = ((m1 >> 3)) * 12 + (m1 & 7);

    // prologue: stage kc=0
    {
        int4 r0 = *(const int4*)(Pb + g0);
        int4 r1;
        if (has2) r1 = *(const int4*)(Pb + g1);
        *(int4*)((char*)lds[0] + (size_t)l0 * 2) = r0;
        if (has2) *(int4*)((char*)lds[0] + (size_t)l1 * 2) = r1;
    }
    __syncthreads();

    for (int kc = 0; kc < 8; ++kc) {
        const int cur = kc & 1;
        int4 n0, n1;
        if (kc < 7) {
            n0 = *(const int4*)(Pb + g0 + (size_t)(kc + 1) * 32);
            if (has2) n1 = *(const int4*)(Pb + g1 + (size_t)(kc + 1) * 32);
        }
        const unsigned short* lb = lds[cur];
#pragma unroll 5
        for (int p = 0; p < 25; ++p) {
            const int poff = (p / 5) * 12 + (p % 5);
            const int px0 = pb0 + poff;
            const int px1 = pb1 + poff;
            s16x8 a0 = *(const s16x8*)(lb + px0 * 32 + (kg ^ ((px0 >> 1) & 3)) * 8);
            s16x8 a1 = *(const s16x8*)(lb + px1 * 32 + (kg ^ ((px1 >> 1) & 3)) * 8);
            const size_t we = (((size_t)(p * 8 + kc) * 8) + wn * 2) * 64 + lane;
            s16x8 b0 = *(const s16x8*)(Wf + we * 8);
            s16x8 b1 = *(const s16x8*)(Wf + we * 8 + 512);
            acc[0][0] = __builtin_amdgcn_mfma_f32_16x16x32_bf16(a0, b0, acc[0][0], 0, 0, 0);
            acc[1][0] = __builtin_amdgcn_mfma_f32_16x16x32_bf16(a1, b0, acc[1][0], 0, 0, 0);
            acc[0][1] = __builtin_amdgcn_mfma_f32_16x16x32_bf16(a0, b1, acc[0][1], 0, 0, 0);
            acc[1][1] = __builtin_amdgcn_mfma_f32_16x16x32_bf16(a1, b1, acc[1][1], 0, 0, 0);
        }
        if (kc < 7) {
            *(int4*)((char*)lds[cur ^ 1] + (size_t)l0 * 2) = n0;
            if (has2) *(int4*)((char*)lds[cur ^ 1] + (size_t)l1 * 2) = n1;
        }
        __syncthreads();
    }

    // epilogue: affine + relu, scatter to xT (n<64) or decC (n>=64), layout (b,hw,64)
#pragma unroll
    for (int nf = 0; nf < 2; ++nf) {
        const int n = wn * 32 + nf * 16 + (lane & 15);
        const float2 sc = aff[n];
        float* dst = (n < 64) ? xT : decC;
        const int ch = n & 63;
#pragma unroll
        for (int mf = 0; mf < 2; ++mf) {
#pragma unroll
            for (int r = 0; r < 4; ++r) {
                const int m = wm * 32 + mf * 16 + (lane >> 4) * 4 + r;
                const int h = h0 + (m >> 3), w = w0 + (m & 7);
                const size_t o = (((size_t)b * HW) + h * WF + w) * 64 + ch;
                dst[o] = fmaxf(sc.x * acc[mf][nf][r] + sc.y, 0.f);
            }
        }
    }
}

// ---------------- depth head: 1x1 conv (64->48) + softmax, dec channel-last ----------------
__global__ __launch_bounds__(256) void depth_kernel(
    const float* __restrict__ dec, const float* __restrict__ dw,
    const float* __restrict__ db, float* __restrict__ depth)
{
    int pid = blockIdx.x * 256 + threadIdx.x;   // 0..26879
    int b  = pid / HW;
    int hw = pid - b * HW;
    const float* dp = dec + (size_t)pid * 64;

    float acc[DD];
#pragma unroll
    for (int d = 0; d < DD; ++d) acc[d] = db[d];

    for (int c = 0; c < CF; ++c) {
        float v = dp[c];
#pragma unroll
        for (int d = 0; d < DD; ++d) acc[d] = fmaf(v, dw[d * CF + c], acc[d]);
    }

    float m = acc[0];
#pragma unroll
    for (int d = 1; d < DD; ++d) m = fmaxf(m, acc[d]);
    float s = 0.f;
#pragma unroll
    for (int d = 0; d < DD; ++d) { acc[d] = expf(acc[d] - m); s += acc[d]; }
    float inv = 1.0f / s;

    float* op = depth + (size_t)b * DD * HW + hw;
#pragma unroll
    for (int d = 0; d < DD; ++d) op[(size_t)d * HW] = acc[d] * inv;
}

// ---------------- geometry (byte-identical to passing round) ----------------
__global__ __launch_bounds__(256) void geom_kernel(
    const float* __restrict__ intr, const float* __restrict__ extr,
    int* __restrict__ cells, int* __restrict__ counts)
{
    int idx = blockIdx.x * 256 + threadIdx.x;
    int d  = idx / HW;
    int hw = idx - d * HW;
    int h  = hw / WF;
    int w  = hw - h * WF;

    float k00 = intr[0], k01 = intr[1], k02 = intr[2];
    float k11 = intr[4], k12 = intr[5];
    float k22 = intr[8];

    float A00 = __fdiv_rn(1.0f, k00);
    float A11 = __fdiv_rn(1.0f, k11);
    float A01 = __fmul_rn(__fmul_rn(k01, A00), -A11);
    float A22 = __fdiv_rn(1.0f, k22);
    float x0  = __fmul_rn(k02, A00);
    x0        = __fadd_rn(x0, __fmul_rn(k12, A01));
    float x1  = __fmul_rn(k12, A11);
    float A02 = __fmul_rn(x0, -A22);
    float A12 = __fmul_rn(x1, -A22);

    float i00 = A00, i01 = A01, i02 = A02;
    float i10 = 0.f, i11 = A11, i12 = A12;
    float i20 = 0.f, i21 = 0.f, i22 = A22;

    float u   = (w + 0.5f) * 8.0f;
    float v   = (h + 0.5f) * 8.0f;
    float dsv = 2.0f + (float)d;
    float px  = __fmul_rn(u, dsv);
    float py  = __fmul_rn(v, dsv);
    float pz  = dsv;

    float cam0 = fmaf(pz, i02, fmaf(py, i01, fmaf(px, i00, 0.0f)));
    float cam1 = fmaf(pz, i12, fmaf(py, i11, fmaf(px, i10, 0.0f)));
    float cam2 = fmaf(pz, i22, fmaf(py, i21, fmaf(px, i20, 0.0f)));

    float r00 = extr[0], r01 = extr[1], r02 = extr[2],  t0 = extr[3];
    float r10 = extr[4], r11 = extr[5], r12 = extr[6],  t1 = extr[7];

    float mm0 = fmaf(cam2, r02, fmaf(cam1, r01, fmaf(cam0, r00, 0.0f)));
    float mm1 = fmaf(cam2, r12, fmaf(cam1, r11, fmaf(cam0, r10, 0.0f)));
    float e0  = __fadd_rn(mm0, t0);
    float e1  = __fadd_rn(mm1, t1);

    float ixf = floorf(__fadd_rn(__fadd_rn(__fdiv_rn(e0, 0.6f), 32.0f), 64.0f));
    float iyf = floorf(__fadd_rn(__fdiv_rn(e1, 0.6f), 64.0f));
    int ix = (int)ixf;
    int iy = (int)iyf;

    bool valid = (ix >= 0) && (ix < BEVX) && (iy >= 0) && (iy < BEVY);
    int cell = valid ? iy * BEVX + ix : -1;
    cells[idx] = cell;
    if (valid) atomicAdd(&counts[cell], 1);
}

// ---------------- exclusive scan ----------------
__global__ __launch_bounds__(256) void scan_kernel(
    const int* __restrict__ counts, int* __restrict__ offsets, int* __restrict__ cursor)
{
    __shared__ int sums[256];
    int t = threadIdx.x;
    int base = t * 64;
    int s = 0;
    for (int i = 0; i < 64; ++i) s += counts[base + i];
    sums[t] = s;
    __syncthreads();
    if (t == 0) {
        int run = 0;
        for (int i = 0; i < 256; ++i) { int v = sums[i]; sums[i] = run; run += v; }
        offsets[NCELL] = run;
    }
    __syncthreads();
    int run = sums[t];
    for (int i = 0; i < 64; ++i) {
        offsets[base + i] = run;
        cursor[base + i]  = run;
        run += counts[base + i];
    }
}

// ---------------- fill point lists ----------------
__global__ __launch_bounds__(256) void fill_kernel(
    const int* __restrict__ cells, int* __restrict__ cursor, int* __restrict__ plist)
{
    int idx = blockIdx.x * 256 + threadIdx.x;
    int c = cells[idx];
    if (c >= 0) {
        int pos = atomicAdd(&cursor[c], 1);
        int d  = idx / HW;
        int hw = idx - d * HW;
        plist[pos] = (d << 16) | hw;
    }
}

// ---------------- gather: one wave per (cell, batch) ----------------
__global__ __launch_bounds__(64) void gather_kernel(
    const float* __restrict__ xT, const float* __restrict__ depth,
    const int* __restrict__ offsets, const int* __restrict__ plist,
    float* __restrict__ out)
{
    int cell = blockIdx.x;
    int b    = blockIdx.y;
    int lane = threadIdx.x;
    int s = offsets[cell];
    int e = offsets[cell + 1];
    const float* xb = xT + (size_t)b * HW * CF;
    const float* dp = depth + (size_t)b * DD * HW;
    float acc = 0.f;
    for (int i = s; i < e; ++i) {
        int p  = plist[i];
        int hw = p & 0xFFFF;
        int d  = p >> 16;
        acc = fmaf(dp[d * HW + hw], xb[(size_t)hw * CF + lane], acc);
    }
    out[((size_t)b * CF + lane) * NCELL + cell] = acc;
}

// ---------------- launch ----------------
extern "C" void kernel_launch(void* const* d_in, const int* in_sizes, int n_in,
                              void* d_out, int out_size, void* d_ws, size_t ws_size,
                              hipStream_t stream)
{
    const float* state   = (const float*)d_in[0];
    const float* intr    = (const float*)d_in[1];
    const float* extr    = (const float*)d_in[2];
    const float* feat_w  = (const float*)d_in[3];
    const float* feat_b  = (const float*)d_in[4];
    const float* feat_g  = (const float*)d_in[5];
    const float* feat_bt = (const float*)d_in[6];
    const float* dec_w   = (const float*)d_in[7];
    const float* dec_b   = (const float*)d_in[8];
    const float* dec_g   = (const float*)d_in[9];
    const float* dec_bt  = (const float*)d_in[10];
    const float* depth_w = (const float*)d_in[11];
    const float* depth_b = (const float*)d_in[12];
    float* out = (float*)d_out;

    // workspace carve-up (all 16B aligned)
    char* ws = (char*)d_ws;
    const size_t P_BYTES   = (size_t)BS * PH * PW * CIN * 2;       // 15,237,120
    const size_t WF_BYTES  = (size_t)25 * 8 * 8 * 64 * 16;         // 1,638,400
    const size_t AFF_BYTES = 128 * sizeof(float2);                 // 1,024
    const size_t F_BYTES   = (size_t)BS * HW * 64 * 4;             // 6,881,280
    const size_t DEP_BYTES = (size_t)BS * DD * HW * 4;             // 5,160,960
    const size_t I_BYTES   = (size_t)NPTS * 4;                     // 1,290,240

    unsigned short* P   = (unsigned short*)ws;            ws += P_BYTES;
    unsigned short* Wf  = (unsigned short*)ws;            ws += WF_BYTES;
    float2*         aff = (float2*)ws;                    ws += AFF_BYTES;
    float*          xT  = (float*)ws;                     ws += F_BYTES;
    float*          decC= (float*)ws;                     ws += F_BYTES;
    float*          dep = (float*)ws;                     ws += DEP_BYTES;
    int*            cells = (int*)ws;                     ws += I_BYTES;
    int*            plist = (int*)ws;                     ws += I_BYTES;
    int*            counts  = (int*)ws;                   ws += NCELL * 4;
    int*            offsets = (int*)ws;                   ws += (NCELL + 4) * 4;
    int*            cursor  = (int*)ws;                   ws += NCELL * 4;

    hipMemsetAsync(counts, 0, NCELL * sizeof(int), stream);
    hipMemsetAsync(P, 0, P_BYTES, stream);

    pad_transpose_kernel<<<dim3(HF, BS), 128, 0, stream>>>(state, P);
    pack_w_kernel<<<400, 256, 0, stream>>>(feat_w, dec_w, Wf);
    pack_aff_kernel<<<1, 128, 0, stream>>>(feat_b, feat_g, feat_bt, dec_b, dec_g, dec_bt, aff);

    conv_mfma_kernel<<<dim3(15, 7, BS), 512, 0, stream>>>(P, Wf, aff, xT, decC);

    depth_kernel<<<(BS * HW) / 256, 256, 0, stream>>>(decC, depth_w, depth_b, dep);

    geom_kernel<<<NPTS / 256, 256, 0, stream>>>(intr, extr, cells, counts);
    scan_kernel<<<1, 256, 0, stream>>>(counts, offsets, cursor);
    fill_kernel<<<NPTS / 256, 256, 0, stream>>>(cells, cursor, plist);

    dim3 ggrid(NCELL, BS);
    gather_kernel<<<ggrid, 64, 0, stream>>>(xT, dep, offsets, plist, out);
}

// Round 5
// 355.610 us; speedup vs baseline: 8.6939x; 1.7634x over previous
//
#include <hip/hip_runtime.h>
#include <hip/hip_bf16.h>
#include <math.h>

#define BS 4
#define CIN 256
#define HF 56
#define WF 120
#define CF 64
#define DD 48
#define HW (HF*WF)          // 6720
#define BEVX 128
#define BEVY 128
#define NCELL (BEVX*BEVY)   // 16384
#define NPTS (DD*HW)        // 322560

#define PH 60               // padded rows
#define PW 124              // padded cols

typedef short s16x8 __attribute__((ext_vector_type(8)));
typedef float f32x4 __attribute__((ext_vector_type(4)));

__device__ __forceinline__ unsigned short f2bf(float f) {
    unsigned int u = __float_as_uint(f);
    unsigned int r = (u + 0x7FFFu + ((u >> 16) & 1u)) >> 16;
    return (unsigned short)r;
}

// ---------------- pad + transpose: state (b,ci,h,w) f32 -> P (b,h+2,w+2,ci) bf16 ----------------
__global__ __launch_bounds__(128) void pad_transpose_kernel(
    const float* __restrict__ state, unsigned short* __restrict__ P)
{
    int w = threadIdx.x;
    int h = blockIdx.x;
    int b = blockIdx.y;
    if (w >= WF) return;
    const float* src = state + (((size_t)b * CIN) * HF + h) * WF + w;
    unsigned short* dst = P + (((size_t)b * PH + (h + 2)) * PW + (w + 2)) * CIN;
    for (int c0 = 0; c0 < CIN; c0 += 8) {
        unsigned short tmp[8];
#pragma unroll
        for (int j = 0; j < 8; ++j)
            tmp[j] = f2bf(src[(size_t)(c0 + j) * HW]);
        *(int4*)(dst + c0) = *(const int4*)tmp;
    }
}

// ---------------- weight pack: (feat|dec) (64,256,5,5) f32 -> Wf bf16 B-fragments ----------------
__global__ __launch_bounds__(256) void pack_w_kernel(
    const float* __restrict__ fw, const float* __restrict__ dw,
    unsigned short* __restrict__ Wf)
{
    int tid = blockIdx.x * 256 + threadIdx.x;
    if (tid >= 25 * 8 * 8 * 64) return;
    int lane = tid & 63;
    int nf = (tid >> 6) & 7;
    int kc = (tid >> 9) & 7;
    int p  = tid >> 12;
    int n   = nf * 16 + (lane & 15);
    int ci0 = kc * 32 + (lane >> 4) * 8;
    const float* src = (n < 64) ? fw + (size_t)n * CIN * 25
                                : dw + (size_t)(n - 64) * CIN * 25;
    unsigned short v[8];
#pragma unroll
    for (int j = 0; j < 8; ++j)
        v[j] = f2bf(src[(size_t)(ci0 + j) * 25 + p]);
    *(int4*)(Wf + (size_t)tid * 8) = *(const int4*)v;
}

__global__ __launch_bounds__(128) void pack_aff_kernel(
    const float* __restrict__ fb, const float* __restrict__ fg, const float* __restrict__ fbt,
    const float* __restrict__ db, const float* __restrict__ dg, const float* __restrict__ dbt,
    float2* __restrict__ aff)
{
    int n = threadIdx.x;
    if (n >= 128) return;
    float g, bi, bt;
    if (n < 64) { g = fg[n]; bi = fb[n]; bt = fbt[n]; }
    else        { g = dg[n - 64]; bi = db[n - 64]; bt = dbt[n - 64]; }
    aff[n] = make_float2(g, g * bi + bt);
}

// ---------------- fused conv (feat+dec) via MFMA implicit GEMM ----------------
// grid (15,7,8): z = b*2 + nhalf. 256 threads (4 waves). Block: 64 px x 64 out-ch.
// Wave (wm,wnl) = 32 px x 32 out-ch. K = 25 taps x 256 ch, stepped 32 ch.
__global__ __launch_bounds__(256) void conv_mfma_kernel(
    const unsigned short* __restrict__ P, const unsigned short* __restrict__ Wf,
    const float2* __restrict__ aff, float* __restrict__ xT, float* __restrict__ decC)
{
    __shared__ __align__(16) unsigned short lds[2][144 * 32];  // [buf][pix][32ch] bf16

    const int tid  = threadIdx.x;
    const int lane = tid & 63;
    const int wid  = tid >> 6;        // 0..3
    const int wm   = wid >> 1;        // 0..1
    const int wn_g = ((blockIdx.z & 1) << 1) + (wid & 1);   // 0..3 global n-quarter
    const int b  = blockIdx.z >> 1;
    const int h0 = blockIdx.y * 8;
    const int w0 = blockIdx.x * 8;

    const unsigned short* Pb = P + (((size_t)b * PH + h0) * PW + w0) * CIN;

    // staging: 576 chunks of 16B (144 pix x 4 slots). thread handles tid, tid+256, tid+512(<576)
    const int pix0 = tid >> 2,          slot0 = tid & 3;
    const size_t g0 = ((size_t)(pix0 / 12) * PW + (pix0 % 12)) * CIN + slot0 * 8;
    const int l0 = pix0 * 32 + (slot0 ^ ((pix0 >> 1) & 3)) * 8;
    const int c1 = 256 + tid;
    const int pix1 = c1 >> 2,           slot1 = c1 & 3;
    const size_t g1 = ((size_t)(pix1 / 12) * PW + (pix1 % 12)) * CIN + slot1 * 8;
    const int l1 = pix1 * 32 + (slot1 ^ ((pix1 >> 1) & 3)) * 8;
    const int c2 = 512 + tid;
    const int pix2 = c2 >> 2,           slot2 = c2 & 3;
    const size_t g2 = ((size_t)(pix2 / 12) * PW + (pix2 % 12)) * CIN + slot2 * 8;
    const int l2 = pix2 * 32 + (slot2 ^ ((pix2 >> 1) & 3)) * 8;
    const bool has3 = (tid < 64);

    f32x4 acc[2][2];
#pragma unroll
    for (int i = 0; i < 2; ++i)
#pragma unroll
        for (int j = 0; j < 2; ++j)
            acc[i][j] = (f32x4){0.f, 0.f, 0.f, 0.f};

    const int kg = lane >> 4;
    const int m0 = wm * 32 + (lane & 15);
    const int m1 = m0 + 16;
    const int pb0 = ((m0 >> 3)) * 12 + (m0 & 7);
    const int pb1 = ((m1 >> 3)) * 12 + (m1 & 7);

    // prologue: stage kc=0
    {
        int4 r0 = *(const int4*)(Pb + g0);
        int4 r1 = *(const int4*)(Pb + g1);
        int4 r2;
        if (has3) r2 = *(const int4*)(Pb + g2);
        *(int4*)((char*)lds[0] + (size_t)l0 * 2) = r0;
        *(int4*)((char*)lds[0] + (size_t)l1 * 2) = r1;
        if (has3) *(int4*)((char*)lds[0] + (size_t)l2 * 2) = r2;
    }
    __syncthreads();

    for (int kc = 0; kc < 8; ++kc) {
        const int cur = kc & 1;
        int4 n0, n1, n2;
        if (kc < 7) {
            n0 = *(const int4*)(Pb + g0 + (size_t)(kc + 1) * 32);
            n1 = *(const int4*)(Pb + g1 + (size_t)(kc + 1) * 32);
            if (has3) n2 = *(const int4*)(Pb + g2 + (size_t)(kc + 1) * 32);
        }
        const unsigned short* lb = lds[cur];
#pragma unroll 5
        for (int p = 0; p < 25; ++p) {
            const int poff = (p / 5) * 12 + (p % 5);
            const int px0 = pb0 + poff;
            const int px1 = pb1 + poff;
            s16x8 a0 = *(const s16x8*)(lb + px0 * 32 + (kg ^ ((px0 >> 1) & 3)) * 8);
            s16x8 a1 = *(const s16x8*)(lb + px1 * 32 + (kg ^ ((px1 >> 1) & 3)) * 8);
            const size_t we = (((size_t)(p * 8 + kc) * 8) + wn_g * 2) * 64 + lane;
            s16x8 b0 = *(const s16x8*)(Wf + we * 8);
            s16x8 b1 = *(const s16x8*)(Wf + we * 8 + 512);
            acc[0][0] = __builtin_amdgcn_mfma_f32_16x16x32_bf16(a0, b0, acc[0][0], 0, 0, 0);
            acc[1][0] = __builtin_amdgcn_mfma_f32_16x16x32_bf16(a1, b0, acc[1][0], 0, 0, 0);
            acc[0][1] = __builtin_amdgcn_mfma_f32_16x16x32_bf16(a0, b1, acc[0][1], 0, 0, 0);
            acc[1][1] = __builtin_amdgcn_mfma_f32_16x16x32_bf16(a1, b1, acc[1][1], 0, 0, 0);
        }
        if (kc < 7) {
            *(int4*)((char*)lds[cur ^ 1] + (size_t)l0 * 2) = n0;
            *(int4*)((char*)lds[cur ^ 1] + (size_t)l1 * 2) = n1;
            if (has3) *(int4*)((char*)lds[cur ^ 1] + (size_t)l2 * 2) = n2;
        }
        __syncthreads();
    }

    // epilogue: affine + relu, write channel-last (b,hw,64)
#pragma unroll
    for (int nf = 0; nf < 2; ++nf) {
        const int n = wn_g * 32 + nf * 16 + (lane & 15);
        const float2 sc = aff[n];
        float* dst = (n < 64) ? xT : decC;
        const int ch = n & 63;
#pragma unroll
        for (int mf = 0; mf < 2; ++mf) {
#pragma unroll
            for (int r = 0; r < 4; ++r) {
                const int m = wm * 32 + mf * 16 + (lane >> 4) * 4 + r;
                const int h = h0 + (m >> 3), w = w0 + (m & 7);
                const size_t o = (((size_t)b * HW) + h * WF + w) * 64 + ch;
                dst[o] = fmaxf(sc.x * acc[mf][nf][r] + sc.y, 0.f);
            }
        }
    }
}

// ---------------- depth head: 1x1 conv (64->48) + softmax, dec channel-last ----------------
__global__ __launch_bounds__(256) void depth_kernel(
    const float* __restrict__ dec, const float* __restrict__ dw,
    const float* __restrict__ db, float* __restrict__ depth)
{
    int pid = blockIdx.x * 256 + threadIdx.x;   // 0..26879
    int b  = pid / HW;
    int hw = pid - b * HW;
    const float* dp = dec + (size_t)pid * 64;

    float acc[DD];
#pragma unroll
    for (int d = 0; d < DD; ++d) acc[d] = db[d];

    for (int c = 0; c < CF; ++c) {
        float v = dp[c];
#pragma unroll
        for (int d = 0; d < DD; ++d) acc[d] = fmaf(v, dw[d * CF + c], acc[d]);
    }

    float m = acc[0];
#pragma unroll
    for (int d = 1; d < DD; ++d) m = fmaxf(m, acc[d]);
    float s = 0.f;
#pragma unroll
    for (int d = 0; d < DD; ++d) { acc[d] = expf(acc[d] - m); s += acc[d]; }
    float inv = 1.0f / s;

    float* op = depth + (size_t)b * DD * HW + hw;
#pragma unroll
    for (int d = 0; d < DD; ++d) op[(size_t)d * HW] = acc[d] * inv;
}

// ---------------- geometry (byte-identical numerics to passing round) ----------------
__global__ __launch_bounds__(256) void geom_kernel(
    const float* __restrict__ intr, const float* __restrict__ extr,
    int* __restrict__ cells, int* __restrict__ counts)
{
    int idx = blockIdx.x * 256 + threadIdx.x;
    int d  = idx / HW;
    int hw = idx - d * HW;
    int h  = hw / WF;
    int w  = hw - h * WF;

    float k00 = intr[0], k01 = intr[1], k02 = intr[2];
    float k11 = intr[4], k12 = intr[5];
    float k22 = intr[8];

    float A00 = __fdiv_rn(1.0f, k00);
    float A11 = __fdiv_rn(1.0f, k11);
    float A01 = __fmul_rn(__fmul_rn(k01, A00), -A11);
    float A22 = __fdiv_rn(1.0f, k22);
    float x0  = __fmul_rn(k02, A00);
    x0        = __fadd_rn(x0, __fmul_rn(k12, A01));
    float x1  = __fmul_rn(k12, A11);
    float A02 = __fmul_rn(x0, -A22);
    float A12 = __fmul_rn(x1, -A22);

    float i00 = A00, i01 = A01, i02 = A02;
    float i10 = 0.f, i11 = A11, i12 = A12;
    float i20 = 0.f, i21 = 0.f, i22 = A22;

    float u   = (w + 0.5f) * 8.0f;
    float v   = (h + 0.5f) * 8.0f;
    float dsv = 2.0f + (float)d;
    float px  = __fmul_rn(u, dsv);
    float py  = __fmul_rn(v, dsv);
    float pz  = dsv;

    float cam0 = fmaf(pz, i02, fmaf(py, i01, fmaf(px, i00, 0.0f)));
    float cam1 = fmaf(pz, i12, fmaf(py, i11, fmaf(px, i10, 0.0f)));
    float cam2 = fmaf(pz, i22, fmaf(py, i21, fmaf(px, i20, 0.0f)));

    float r00 = extr[0], r01 = extr[1], r02 = extr[2],  t0 = extr[3];
    float r10 = extr[4], r11 = extr[5], r12 = extr[6],  t1 = extr[7];

    float mm0 = fmaf(cam2, r02, fmaf(cam1, r01, fmaf(cam0, r00, 0.0f)));
    float mm1 = fmaf(cam2, r12, fmaf(cam1, r11, fmaf(cam0, r10, 0.0f)));
    float e0  = __fadd_rn(mm0, t0);
    float e1  = __fadd_rn(mm1, t1);

    float ixf = floorf(__fadd_rn(__fadd_rn(__fdiv_rn(e0, 0.6f), 32.0f), 64.0f));
    float iyf = floorf(__fadd_rn(__fdiv_rn(e1, 0.6f), 64.0f));
    int ix = (int)ixf;
    int iy = (int)iyf;

    bool valid = (ix >= 0) && (ix < BEVX) && (iy >= 0) && (iy < BEVY);
    int cell = valid ? iy * BEVX + ix : -1;
    cells[idx] = cell;
    if (valid) atomicAdd(&counts[cell], 1);
}

// ---------------- exclusive scan ----------------
__global__ __launch_bounds__(256) void scan_kernel(
    const int* __restrict__ counts, int* __restrict__ offsets, int* __restrict__ cursor)
{
    __shared__ int sums[256];
    int t = threadIdx.x;
    int base = t * 64;
    int s = 0;
    for (int i = 0; i < 64; ++i) s += counts[base + i];
    sums[t] = s;
    __syncthreads();
    if (t == 0) {
        int run = 0;
        for (int i = 0; i < 256; ++i) { int v = sums[i]; sums[i] = run; run += v; }
        offsets[NCELL] = run;
    }
    __syncthreads();
    int run = sums[t];
    for (int i = 0; i < 64; ++i) {
        offsets[base + i] = run;
        cursor[base + i]  = run;
        run += counts[base + i];
    }
}

// ---------------- fill point lists (+ cell id per point) ----------------
__global__ __launch_bounds__(256) void fill_kernel(
    const int* __restrict__ cells, int* __restrict__ cursor,
    int* __restrict__ plist, int* __restrict__ pcell)
{
    int idx = blockIdx.x * 256 + threadIdx.x;
    int c = cells[idx];
    if (c >= 0) {
        int pos = atomicAdd(&cursor[c], 1);
        int d  = idx / HW;
        int hw = idx - d * HW;
        plist[pos] = (d << 16) | hw;
        pcell[pos] = c;
    }
}

// ---------------- gather2: one wave per 64-point chunk of sorted plist ----------------
// lanes = channels. Flush (coalesced atomicAdd, 64 consecutive floats) on cell change.
__global__ __launch_bounds__(64) void gather2_kernel(
    const float* __restrict__ xT, const float* __restrict__ depth,
    const int* __restrict__ plist, const int* __restrict__ pcell,
    const int* __restrict__ nptr, float* __restrict__ pooled)
{
    const int b    = blockIdx.y;
    const int lane = threadIdx.x;
    const int npts = *nptr;
    const int i0   = blockIdx.x * 64;
    if (i0 >= npts) return;
    const int n = min(64, npts - i0);

    int myp = 0, myc = -1;
    if (i0 + lane < npts) { myp = plist[i0 + lane]; myc = pcell[i0 + lane]; }

    const float* xb = xT + (size_t)b * HW * CF;
    const float* dp = depth + (size_t)b * DD * HW;
    float* pb = pooled + (size_t)b * NCELL * CF;

    float acc = 0.f;
    int cur = __shfl(myc, 0);
    for (int j = 0; j < n; ++j) {
        int p = __shfl(myp, j);
        int c = __shfl(myc, j);
        if (c != cur) {
            atomicAdd(&pb[(size_t)cur * CF + lane], acc);
            acc = 0.f;
            cur = c;
        }
        int hw = p & 0xFFFF;
        int d  = p >> 16;
        acc = fmaf(dp[d * HW + hw], xb[(size_t)hw * CF + lane], acc);
    }
    atomicAdd(&pb[(size_t)cur * CF + lane], acc);
}

// ---------------- transpose pooled (b,cell,64) -> out (b,64,cell) ----------------
__global__ __launch_bounds__(256) void transpose_kernel(
    const float* __restrict__ pooled, float* __restrict__ out)
{
    __shared__ float t[64][65];
    const int b  = blockIdx.y;
    const int c0 = blockIdx.x * 64;   // cell block
    const int tid = threadIdx.x;
#pragma unroll
    for (int k = 0; k < 16; ++k) {
        int idx = tid + k * 256;
        int cell = idx >> 6, ch = idx & 63;
        t[cell][ch] = pooled[(((size_t)b * NCELL) + c0 + cell) * CF + ch];
    }
    __syncthreads();
#pragma unroll
    for (int k = 0; k < 16; ++k) {
        int idx = tid + k * 256;
        int ch = idx >> 6, cell = idx & 63;
        out[((size_t)b * CF + ch) * NCELL + c0 + cell] = t[cell][ch];
    }
}

// ---------------- launch ----------------
extern "C" void kernel_launch(void* const* d_in, const int* in_sizes, int n_in,
                              void* d_out, int out_size, void* d_ws, size_t ws_size,
                              hipStream_t stream)
{
    const float* state   = (const float*)d_in[0];
    const float* intr    = (const float*)d_in[1];
    const float* extr    = (const float*)d_in[2];
    const float* feat_w  = (const float*)d_in[3];
    const float* feat_b  = (const float*)d_in[4];
    const float* feat_g  = (const float*)d_in[5];
    const float* feat_bt = (const float*)d_in[6];
    const float* dec_w   = (const float*)d_in[7];
    const float* dec_b   = (const float*)d_in[8];
    const float* dec_g   = (const float*)d_in[9];
    const float* dec_bt  = (const float*)d_in[10];
    const float* depth_w = (const float*)d_in[11];
    const float* depth_b = (const float*)d_in[12];
    float* out = (float*)d_out;

    // workspace carve-up (all 16B aligned)
    char* ws = (char*)d_ws;
    const size_t P_BYTES   = (size_t)BS * PH * PW * CIN * 2;       // 15,237,120
    const size_t WF_BYTES  = (size_t)25 * 8 * 8 * 64 * 16;         // 1,638,400
    const size_t AFF_BYTES = 1024;
    const size_t F_BYTES   = (size_t)BS * HW * 64 * 4;             // 6,881,280
    const size_t DEP_BYTES = (size_t)BS * DD * HW * 4;             // 5,160,960
    const size_t I_BYTES   = (size_t)NPTS * 4;                     // 1,290,240
    const size_t POOL_BYTES= (size_t)BS * NCELL * CF * 4;          // 16,777,216

    unsigned short* P   = (unsigned short*)ws;            ws += P_BYTES;
    unsigned short* Wfr = (unsigned short*)ws;            ws += WF_BYTES;
    float2*         aff = (float2*)ws;                    ws += AFF_BYTES;
    float*          xT  = (float*)ws;                     ws += F_BYTES;
    float*          decC= (float*)ws;                     ws += F_BYTES;
    float*          dep = (float*)ws;                     ws += DEP_BYTES;
    int*            cells = (int*)ws;                     ws += I_BYTES;
    int*            plist = (int*)ws;                     ws += I_BYTES;
    int*            pcell = (int*)ws;                     ws += I_BYTES;
    int*            counts  = (int*)ws;                   ws += NCELL * 4;
    int*            offsets = (int*)ws;                   ws += (NCELL + 4) * 4;
    int*            cursor  = (int*)ws;                   ws += NCELL * 4;

    // pooled aliases P+Wf (free after conv); POOL_BYTES (16.78MB) <= P+Wf (16.88MB)
    float* pooled = (float*)d_ws;

    hipMemsetAsync(counts, 0, NCELL * sizeof(int), stream);
    hipMemsetAsync(P, 0, P_BYTES, stream);

    pad_transpose_kernel<<<dim3(HF, BS), 128, 0, stream>>>(state, P);
    pack_w_kernel<<<400, 256, 0, stream>>>(feat_w, dec_w, Wfr);
    pack_aff_kernel<<<1, 128, 0, stream>>>(feat_b, feat_g, feat_bt, dec_b, dec_g, dec_bt, aff);

    conv_mfma_kernel<<<dim3(15, 7, BS * 2), 256, 0, stream>>>(P, Wfr, aff, xT, decC);

    depth_kernel<<<(BS * HW) / 256, 256, 0, stream>>>(decC, depth_w, depth_b, dep);

    geom_kernel<<<NPTS / 256, 256, 0, stream>>>(intr, extr, cells, counts);
    scan_kernel<<<1, 256, 0, stream>>>(counts, offsets, cursor);
    fill_kernel<<<NPTS / 256, 256, 0, stream>>>(cells, cursor, plist, pcell);

    // conv consumed P/Wf; now reuse that region as pooled accumulator
    hipMemsetAsync(pooled, 0, POOL_BYTES, stream);

    gather2_kernel<<<dim3((NPTS + 63) / 64, BS), 64, 0, stream>>>(
        xT, dep, plist, pcell, offsets + NCELL, pooled);

    transpose_kernel<<<dim3(NCELL / 64, BS), 256, 0, stream>>>(pooled, out);
}

// Round 6
// 349.581 us; speedup vs baseline: 8.8439x; 1.0172x over previous
//
#include <hip/hip_runtime.h>
#include <hip/hip_bf16.h>
#include <math.h>

#define BS 4
#define CIN 256
#define HF 56
#define WF 120
#define CF 64
#define DD 48
#define HW (HF*WF)          // 6720
#define BEVX 128
#define BEVY 128
#define NCELL (BEVX*BEVY)   // 16384
#define NPTS (DD*HW)        // 322560

#define PH 60               // padded rows
#define PW 124              // padded cols

#define GEOM_BLOCKS  (NPTS/256)      // 1260
#define PACKW_BLOCKS 400             // 102400 threads

typedef short s16x8 __attribute__((ext_vector_type(8)));
typedef float f32x4 __attribute__((ext_vector_type(4)));

__device__ __forceinline__ unsigned short f2bf(float f) {
    unsigned int u = __float_as_uint(f);
    unsigned int r = (u + 0x7FFFu + ((u >> 16) & 1u)) >> 16;
    return (unsigned short)r;
}

// ---------------- pad + transpose + halo-zero + counts-zero ----------------
// grid (PH, BS), 128 threads. Row h2 of padded image; borders zeroed here.
__global__ __launch_bounds__(128) void pad_kernel(
    const float* __restrict__ state, unsigned short* __restrict__ P,
    int* __restrict__ counts)
{
    const int h2  = blockIdx.x;      // 0..59
    const int b   = blockIdx.y;
    const int tid = threadIdx.x;
    unsigned short* rowp = P + (((size_t)b * PH + h2) * PW) * CIN;
    const int4 z4 = make_int4(0, 0, 0, 0);

    if (h2 >= 2 && h2 < 2 + HF) {
        const int h = h2 - 2;
        if (tid < WF) {
            const float* src = state + (((size_t)b * CIN) * HF + h) * WF + tid;
            unsigned short* dst = rowp + (size_t)(tid + 2) * CIN;
            for (int c0 = 0; c0 < CIN; c0 += 8) {
                unsigned short tmp[8];
#pragma unroll
                for (int j = 0; j < 8; ++j)
                    tmp[j] = f2bf(src[(size_t)(c0 + j) * HW]);
                *(int4*)(dst + c0) = *(const int4*)tmp;
            }
        } else if (tid < 124) {
            // halo columns 0,1,122,123
            const int w2 = (tid == 120) ? 0 : (tid == 121) ? 1 : tid;
            int4* d4 = (int4*)(rowp + (size_t)w2 * CIN);
#pragma unroll
            for (int i = 0; i < 32; ++i) d4[i] = z4;
        }
    } else {
        // full border row: PW*CIN*2B = 63488B = 3968 int4
        int4* r4 = (int4*)rowp;
        for (int i = tid; i < 3968; i += 128) r4[i] = z4;
    }

    if (b == 0 && h2 < 32) {
        int4* c4 = (int4*)counts;
        c4[h2 * 128 + tid] = z4;     // 32*128*4 ints = 16384
    }
}

// ---------------- prep: geom + weight pack + affine pack (block-range dispatch) ----------------
__global__ __launch_bounds__(256) void prep_kernel(
    const float* __restrict__ intr, const float* __restrict__ extr,
    const float* __restrict__ fw, const float* __restrict__ dw,
    const float* __restrict__ fb, const float* __restrict__ fg, const float* __restrict__ fbt,
    const float* __restrict__ db, const float* __restrict__ dg, const float* __restrict__ dbt,
    int* __restrict__ cells, int* __restrict__ counts,
    unsigned short* __restrict__ Wf, float2* __restrict__ aff)
{
    const int bid = blockIdx.x;
    const int tid = threadIdx.x;

    if (bid < GEOM_BLOCKS) {
        // ---- geometry: byte-identical numerics to the passing version ----
        int idx = bid * 256 + tid;
        int d  = idx / HW;
        int hw = idx - d * HW;
        int h  = hw / WF;
        int w  = hw - h * WF;

        float k00 = intr[0], k01 = intr[1], k02 = intr[2];
        float k11 = intr[4], k12 = intr[5];
        float k22 = intr[8];

        float A00 = __fdiv_rn(1.0f, k00);
        float A11 = __fdiv_rn(1.0f, k11);
        float A01 = __fmul_rn(__fmul_rn(k01, A00), -A11);
        float A22 = __fdiv_rn(1.0f, k22);
        float x0  = __fmul_rn(k02, A00);
        x0        = __fadd_rn(x0, __fmul_rn(k12, A01));
        float x1  = __fmul_rn(k12, A11);
        float A02 = __fmul_rn(x0, -A22);
        float A12 = __fmul_rn(x1, -A22);

        float i00 = A00, i01 = A01, i02 = A02;
        float i10 = 0.f, i11 = A11, i12 = A12;
        float i20 = 0.f, i21 = 0.f, i22 = A22;

        float u   = (w + 0.5f) * 8.0f;
        float v   = (h + 0.5f) * 8.0f;
        float dsv = 2.0f + (float)d;
        float px  = __fmul_rn(u, dsv);
        float py  = __fmul_rn(v, dsv);
        float pz  = dsv;

        float cam0 = fmaf(pz, i02, fmaf(py, i01, fmaf(px, i00, 0.0f)));
        float cam1 = fmaf(pz, i12, fmaf(py, i11, fmaf(px, i10, 0.0f)));
        float cam2 = fmaf(pz, i22, fmaf(py, i21, fmaf(px, i20, 0.0f)));

        float r00 = extr[0], r01 = extr[1], r02 = extr[2],  t0 = extr[3];
        float r10 = extr[4], r11 = extr[5], r12 = extr[6],  t1 = extr[7];

        float mm0 = fmaf(cam2, r02, fmaf(cam1, r01, fmaf(cam0, r00, 0.0f)));
        float mm1 = fmaf(cam2, r12, fmaf(cam1, r11, fmaf(cam0, r10, 0.0f)));
        float e0  = __fadd_rn(mm0, t0);
        float e1  = __fadd_rn(mm1, t1);

        float ixf = floorf(__fadd_rn(__fadd_rn(__fdiv_rn(e0, 0.6f), 32.0f), 64.0f));
        float iyf = floorf(__fadd_rn(__fdiv_rn(e1, 0.6f), 64.0f));
        int ix = (int)ixf;
        int iy = (int)iyf;

        bool valid = (ix >= 0) && (ix < BEVX) && (iy >= 0) && (iy < BEVY);
        int cell = valid ? iy * BEVX + ix : -1;
        cells[idx] = cell;
        if (valid) atomicAdd(&counts[cell], 1);
    } else if (bid < GEOM_BLOCKS + PACKW_BLOCKS) {
        // ---- weight pack ----
        int t = (bid - GEOM_BLOCKS) * 256 + tid;
        int lane = t & 63;
        int nf = (t >> 6) & 7;
        int kc = (t >> 9) & 7;
        int p  = t >> 12;
        int n   = nf * 16 + (lane & 15);
        int ci0 = kc * 32 + (lane >> 4) * 8;
        const float* src = (n < 64) ? fw + (size_t)n * CIN * 25
                                    : dw + (size_t)(n - 64) * CIN * 25;
        unsigned short v[8];
#pragma unroll
        for (int j = 0; j < 8; ++j)
            v[j] = f2bf(src[(size_t)(ci0 + j) * 25 + p]);
        *(int4*)(Wf + (size_t)t * 8) = *(const int4*)v;
    } else {
        // ---- affine pack ----
        if (tid < 128) {
            float g, bi, bt;
            if (tid < 64) { g = fg[tid]; bi = fb[tid]; bt = fbt[tid]; }
            else          { g = dg[tid - 64]; bi = db[tid - 64]; bt = dbt[tid - 64]; }
            aff[tid] = make_float2(g, g * bi + bt);
        }
    }
}

// ---------------- fused conv (feat+dec) + depth head via MFMA implicit GEMM ----------------
// grid (15,7,BS), 256 threads (4 waves). Block: 64 px (8x8) x 128 out-ch.
// Wave (wm, wn): 32 px x 64 ch. 8 MFMA per {2 ds_read + 4 B-load} per tap.
// After epilogue: dec half -> LDS -> 1x1 depth conv + softmax, all in-block.
__global__ __launch_bounds__(256) void conv_mfma_kernel(
    const unsigned short* __restrict__ P, const unsigned short* __restrict__ Wf,
    const float2* __restrict__ aff, const float* __restrict__ dwt,
    const float* __restrict__ dbs, float* __restrict__ xT, float* __restrict__ dep)
{
    __shared__ __align__(16) unsigned short lds[2][144 * 32];  // 18432B; reused for depth phase

    const int tid  = threadIdx.x;
    const int lane = tid & 63;
    const int wid  = tid >> 6;        // 0..3
    const int wm   = wid >> 1;        // 0..1
    const int wn   = wid & 1;         // 0..1 (64-ch half)
    const int b  = blockIdx.z;
    const int h0 = blockIdx.y * 8;
    const int w0 = blockIdx.x * 8;

    const unsigned short* Pb = P + (((size_t)b * PH + h0) * PW + w0) * CIN;

    // staging: 576 chunks of 16B (144 px x 4 slots); thread covers tid, tid+256, tid+512(<576)
    const int pix0 = tid >> 2,          slot0 = tid & 3;
    const size_t g0 = ((size_t)(pix0 / 12) * PW + (pix0 % 12)) * CIN + slot0 * 8;
    const int l0 = pix0 * 32 + (slot0 ^ ((pix0 >> 1) & 3)) * 8;
    const int c1 = 256 + tid;
    const int pix1 = c1 >> 2,           slot1 = c1 & 3;
    const size_t g1 = ((size_t)(pix1 / 12) * PW + (pix1 % 12)) * CIN + slot1 * 8;
    const int l1 = pix1 * 32 + (slot1 ^ ((pix1 >> 1) & 3)) * 8;
    const int c2 = 512 + tid;
    const int pix2 = c2 >> 2,           slot2 = c2 & 3;
    const size_t g2 = ((size_t)(pix2 / 12) * PW + (pix2 % 12)) * CIN + slot2 * 8;
    const int l2 = pix2 * 32 + (slot2 ^ ((pix2 >> 1) & 3)) * 8;
    const bool has3 = (tid < 64);

    f32x4 acc[2][4];
#pragma unroll
    for (int i = 0; i < 2; ++i)
#pragma unroll
        for (int j = 0; j < 4; ++j)
            acc[i][j] = (f32x4){0.f, 0.f, 0.f, 0.f};

    const int kg = lane >> 4;
    const int m0 = wm * 32 + (lane & 15);
    const int m1 = m0 + 16;
    const int pb0 = ((m0 >> 3)) * 12 + (m0 & 7);
    const int pb1 = ((m1 >> 3)) * 12 + (m1 & 7);

    // prologue: stage kc=0
    {
        int4 r0 = *(const int4*)(Pb + g0);
        int4 r1 = *(const int4*)(Pb + g1);
        int4 r2;
        if (has3) r2 = *(const int4*)(Pb + g2);
        *(int4*)((char*)lds[0] + (size_t)l0 * 2) = r0;
        *(int4*)((char*)lds[0] + (size_t)l1 * 2) = r1;
        if (has3) *(int4*)((char*)lds[0] + (size_t)l2 * 2) = r2;
    }
    __syncthreads();

    for (int kc = 0; kc < 8; ++kc) {
        const int cur = kc & 1;
        int4 n0, n1, n2;
        if (kc < 7) {
            n0 = *(const int4*)(Pb + g0 + (size_t)(kc + 1) * 32);
            n1 = *(const int4*)(Pb + g1 + (size_t)(kc + 1) * 32);
            if (has3) n2 = *(const int4*)(Pb + g2 + (size_t)(kc + 1) * 32);
        }
        const unsigned short* lb = lds[cur];
#pragma unroll 5
        for (int p = 0; p < 25; ++p) {
            const int poff = (p / 5) * 12 + (p % 5);
            const int px0 = pb0 + poff;
            const int px1 = pb1 + poff;
            s16x8 a0 = *(const s16x8*)(lb + px0 * 32 + (kg ^ ((px0 >> 1) & 3)) * 8);
            s16x8 a1 = *(const s16x8*)(lb + px1 * 32 + (kg ^ ((px1 >> 1) & 3)) * 8);
            const unsigned short* wp =
                Wf + ((((size_t)(p * 8 + kc)) * 8 + wn * 4) * 64 + lane) * 8;
            s16x8 b0 = *(const s16x8*)(wp);
            s16x8 b1 = *(const s16x8*)(wp + 512);
            s16x8 b2 = *(const s16x8*)(wp + 1024);
            s16x8 b3 = *(const s16x8*)(wp + 1536);
            acc[0][0] = __builtin_amdgcn_mfma_f32_16x16x32_bf16(a0, b0, acc[0][0], 0, 0, 0);
            acc[1][0] = __builtin_amdgcn_mfma_f32_16x16x32_bf16(a1, b0, acc[1][0], 0, 0, 0);
            acc[0][1] = __builtin_amdgcn_mfma_f32_16x16x32_bf16(a0, b1, acc[0][1], 0, 0, 0);
            acc[1][1] = __builtin_amdgcn_mfma_f32_16x16x32_bf16(a1, b1, acc[1][1], 0, 0, 0);
            acc[0][2] = __builtin_amdgcn_mfma_f32_16x16x32_bf16(a0, b2, acc[0][2], 0, 0, 0);
            acc[1][2] = __builtin_amdgcn_mfma_f32_16x16x32_bf16(a1, b2, acc[1][2], 0, 0, 0);
            acc[0][3] = __builtin_amdgcn_mfma_f32_16x16x32_bf16(a0, b3, acc[0][3], 0, 0, 0);
            acc[1][3] = __builtin_amdgcn_mfma_f32_16x16x32_bf16(a1, b3, acc[1][3], 0, 0, 0);
        }
        if (kc < 7) {
            *(int4*)((char*)lds[cur ^ 1] + (size_t)l0 * 2) = n0;
            *(int4*)((char*)lds[cur ^ 1] + (size_t)l1 * 2) = n1;
            if (has3) *(int4*)((char*)lds[cur ^ 1] + (size_t)l2 * 2) = n2;
        }
        __syncthreads();
    }

    // ---------------- epilogue ----------------
    float* ldsf = (float*)&lds[0][0];     // 64 px x 65 f32 = 16640B (fits 18432)

    if (wn == 0) {
        // feat half -> xT (b, hw, 64ch)
#pragma unroll
        for (int nf = 0; nf < 4; ++nf) {
            const int n = nf * 16 + (lane & 15);
            const float2 sc = aff[n];
#pragma unroll
            for (int mf = 0; mf < 2; ++mf) {
#pragma unroll
                for (int r = 0; r < 4; ++r) {
                    const int m = wm * 32 + mf * 16 + (lane >> 4) * 4 + r;
                    const int h = h0 + (m >> 3), w = w0 + (m & 7);
                    xT[(((size_t)b * HW) + h * WF + w) * 64 + n] =
                        fmaxf(sc.x * acc[mf][nf][r] + sc.y, 0.f);
                }
            }
        }
    } else {
        // dec half -> LDS [px][ch] (pad 65)
#pragma unroll
        for (int nf = 0; nf < 4; ++nf) {
            const int ch = nf * 16 + (lane & 15);
            const float2 sc = aff[64 + ch];
#pragma unroll
            for (int mf = 0; mf < 2; ++mf) {
#pragma unroll
                for (int r = 0; r < 4; ++r) {
                    const int m = wm * 32 + mf * 16 + (lane >> 4) * 4 + r;
                    ldsf[m * 65 + ch] = fmaxf(sc.x * acc[mf][nf][r] + sc.y, 0.f);
                }
            }
        }
    }
    __syncthreads();

    // ---------------- depth head: 48 logits + softmax, 4 waves x 12 d's ----------------
    const int px = lane;            // 0..63: block pixel
    const int q  = wid;             // 0..3: d-quarter
    float l[12];
#pragma unroll
    for (int j = 0; j < 12; ++j) l[j] = dbs[q * 12 + j];
    for (int c = 0; c < CF; ++c) {
        float v = ldsf[px * 65 + c];
#pragma unroll
        for (int j = 0; j < 12; ++j)
            l[j] = fmaf(v, dwt[(q * 12 + j) * CF + c], l[j]);
    }
    float pm = l[0];
#pragma unroll
    for (int j = 1; j < 12; ++j) pm = fmaxf(pm, l[j]);

    __syncthreads();                       // ldsf reads done; reuse front as reduce buf
    float* red = (float*)&lds[0][0];       // [q][64] partial max, then [256+q*64] partial sum
    red[q * 64 + px] = pm;
    __syncthreads();
    float m = fmaxf(fmaxf(red[px], red[64 + px]), fmaxf(red[128 + px], red[192 + px]));

    float ps = 0.f;
#pragma unroll
    for (int j = 0; j < 12; ++j) { l[j] = expf(l[j] - m); ps += l[j]; }
    red[256 + q * 64 + px] = ps;
    __syncthreads();
    float s = red[256 + px];
    s += red[256 + 64 + px];
    s += red[256 + 128 + px];
    s += red[256 + 192 + px];
    float inv = 1.0f / s;

    const int hw = (h0 + (px >> 3)) * WF + (w0 + (px & 7));
    float* op = dep + (size_t)b * DD * HW + hw;
#pragma unroll
    for (int j = 0; j < 12; ++j)
        op[(size_t)(q * 12 + j) * HW] = l[j] * inv;
}

// ---------------- scan: 1024 threads, shfl + LDS two-level ----------------
__global__ __launch_bounds__(1024) void scan_kernel(
    const int* __restrict__ counts, int* __restrict__ offsets, int* __restrict__ cursor)
{
    __shared__ int wsum[16];
    const int tid = threadIdx.x;
    const int lane = tid & 63;
    const int wv = tid >> 6;

    int cnt[16];
    const int4* cp = (const int4*)counts;
#pragma unroll
    for (int k = 0; k < 4; ++k) {
        int4 c4 = cp[tid * 4 + k];
        cnt[k * 4 + 0] = c4.x; cnt[k * 4 + 1] = c4.y;
        cnt[k * 4 + 2] = c4.z; cnt[k * 4 + 3] = c4.w;
    }
    int s = 0;
#pragma unroll
    for (int i = 0; i < 16; ++i) s += cnt[i];

    int inc = s;
#pragma unroll
    for (int off = 1; off < 64; off <<= 1) {
        int v = __shfl_up(inc, off);
        if (lane >= off) inc += v;
    }
    if (lane == 63) wsum[wv] = inc;
    __syncthreads();
    if (tid == 0) {
        int run = 0;
#pragma unroll
        for (int i = 0; i < 16; ++i) { int v = wsum[i]; wsum[i] = run; run += v; }
        offsets[NCELL] = run;
    }
    __syncthreads();
    int run = wsum[wv] + (inc - s);
#pragma unroll
    for (int i = 0; i < 16; ++i) {
        offsets[tid * 16 + i] = run;
        cursor[tid * 16 + i]  = run;
        run += cnt[i];
    }
}

// ---------------- fill point lists (+ cell id per point) ----------------
__global__ __launch_bounds__(256) void fill_kernel(
    const int* __restrict__ cells, int* __restrict__ cursor,
    int* __restrict__ plist, int* __restrict__ pcell)
{
    int idx = blockIdx.x * 256 + threadIdx.x;
    int c = cells[idx];
    if (c >= 0) {
        int pos = atomicAdd(&cursor[c], 1);
        int d  = idx / HW;
        int hw = idx - d * HW;
        plist[pos] = (d << 16) | hw;
        pcell[pos] = c;
    }
}

// ---------------- gather2: one wave per 64-point chunk of cell-sorted plist ----------------
__global__ __launch_bounds__(64) void gather2_kernel(
    const float* __restrict__ xT, const float* __restrict__ depth,
    const int* __restrict__ plist, const int* __restrict__ pcell,
    const int* __restrict__ nptr, float* __restrict__ pooled)
{
    const int b    = blockIdx.y;
    const int lane = threadIdx.x;
    const int npts = *nptr;
    const int i0   = blockIdx.x * 64;
    if (i0 >= npts) return;
    const int n = min(64, npts - i0);

    int myp = 0, myc = -1;
    if (i0 + lane < npts) { myp = plist[i0 + lane]; myc = pcell[i0 + lane]; }

    const float* xb = xT + (size_t)b * HW * CF;
    const float* dp = depth + (size_t)b * DD * HW;
    float* pb = pooled + (size_t)b * NCELL * CF;

    float acc = 0.f;
    int cur = __shfl(myc, 0);
    for (int j = 0; j < n; ++j) {
        int p = __shfl(myp, j);
        int c = __shfl(myc, j);
        if (c != cur) {
            atomicAdd(&pb[(size_t)cur * CF + lane], acc);
            acc = 0.f;
            cur = c;
        }
        int hw = p & 0xFFFF;
        int d  = p >> 16;
        acc = fmaf(dp[d * HW + hw], xb[(size_t)hw * CF + lane], acc);
    }
    atomicAdd(&pb[(size_t)cur * CF + lane], acc);
}

// ---------------- transpose pooled (b,cell,64) -> out (b,64,cell) ----------------
__global__ __launch_bounds__(256) void transpose_kernel(
    const float* __restrict__ pooled, float* __restrict__ out)
{
    __shared__ float t[64][65];
    const int b  = blockIdx.y;
    const int c0 = blockIdx.x * 64;
    const int tid = threadIdx.x;
#pragma unroll
    for (int k = 0; k < 16; ++k) {
        int idx = tid + k * 256;
        int cell = idx >> 6, ch = idx & 63;
        t[cell][ch] = pooled[(((size_t)b * NCELL) + c0 + cell) * CF + ch];
    }
    __syncthreads();
#pragma unroll
    for (int k = 0; k < 16; ++k) {
        int idx = tid + k * 256;
        int ch = idx >> 6, cell = idx & 63;
        out[((size_t)b * CF + ch) * NCELL + c0 + cell] = t[cell][ch];
    }
}

// ---------------- launch ----------------
extern "C" void kernel_launch(void* const* d_in, const int* in_sizes, int n_in,
                              void* d_out, int out_size, void* d_ws, size_t ws_size,
                              hipStream_t stream)
{
    const float* state   = (const float*)d_in[0];
    const float* intr    = (const float*)d_in[1];
    const float* extr    = (const float*)d_in[2];
    const float* feat_w  = (const float*)d_in[3];
    const float* feat_b  = (const float*)d_in[4];
    const float* feat_g  = (const float*)d_in[5];
    const float* feat_bt = (const float*)d_in[6];
    const float* dec_w   = (const float*)d_in[7];
    const float* dec_b   = (const float*)d_in[8];
    const float* dec_g   = (const float*)d_in[9];
    const float* dec_bt  = (const float*)d_in[10];
    const float* depth_w = (const float*)d_in[11];
    const float* depth_b = (const float*)d_in[12];
    float* out = (float*)d_out;

    // workspace carve-up (all 16B aligned)
    char* ws = (char*)d_ws;
    const size_t P_BYTES   = (size_t)BS * PH * PW * CIN * 2;       // 15,237,120
    const size_t WF_BYTES  = (size_t)25 * 8 * 8 * 64 * 16;         // 1,638,400
    const size_t AFF_BYTES = 1024;
    const size_t F_BYTES   = (size_t)BS * HW * 64 * 4;             // 6,881,280
    const size_t DEP_BYTES = (size_t)BS * DD * HW * 4;             // 5,160,960
    const size_t I_BYTES   = (size_t)NPTS * 4;                     // 1,290,240
    const size_t POOL_BYTES= (size_t)BS * NCELL * CF * 4;          // 16,777,216

    unsigned short* P   = (unsigned short*)ws;            ws += P_BYTES;
    unsigned short* Wfr = (unsigned short*)ws;            ws += WF_BYTES;
    float2*         aff = (float2*)ws;                    ws += AFF_BYTES;
    float*          xT  = (float*)ws;                     ws += F_BYTES;
    float*          dep = (float*)ws;                     ws += DEP_BYTES;
    int*            cells = (int*)ws;                     ws += I_BYTES;
    int*            plist = (int*)ws;                     ws += I_BYTES;
    int*            pcell = (int*)ws;                     ws += I_BYTES;
    int*            counts  = (int*)ws;                   ws += NCELL * 4;
    int*            offsets = (int*)ws;                   ws += (NCELL + 4) * 4;
    int*            cursor  = (int*)ws;                   ws += NCELL * 4;

    // pooled aliases P+Wf (dead after conv); 16.78MB <= 16.88MB
    float* pooled = (float*)d_ws;

    pad_kernel<<<dim3(PH, BS), 128, 0, stream>>>(state, P, counts);

    prep_kernel<<<GEOM_BLOCKS + PACKW_BLOCKS + 1, 256, 0, stream>>>(
        intr, extr, feat_w, dec_w,
        feat_b, feat_g, feat_bt, dec_b, dec_g, dec_bt,
        cells, counts, Wfr, aff);

    conv_mfma_kernel<<<dim3(15, 7, BS), 256, 0, stream>>>(
        P, Wfr, aff, depth_w, depth_b, xT, dep);

    scan_kernel<<<1, 1024, 0, stream>>>(counts, offsets, cursor);

    fill_kernel<<<GEOM_BLOCKS, 256, 0, stream>>>(cells, cursor, plist, pcell);

    hipMemsetAsync(pooled, 0, POOL_BYTES, stream);

    gather2_kernel<<<dim3((NPTS + 63) / 64, BS), 64, 0, stream>>>(
        xT, dep, plist, pcell, offsets + NCELL, pooled);

    transpose_kernel<<<dim3(NCELL / 64, BS), 256, 0, stream>>>(pooled, out);
}

// Round 7
// 333.175 us; speedup vs baseline: 9.2794x; 1.0492x over previous
//
#include <hip/hip_runtime.h>
#include <hip/hip_bf16.h>
#include <math.h>

#define BS 4
#define CIN 256
#define HF 56
#define WF 120
#define CF 64
#define DD 48
#define HW (HF*WF)          // 6720
#define BEVX 128
#define BEVY 128
#define NCELL (BEVX*BEVY)   // 16384
#define NPTS (DD*HW)        // 322560

#define PH 60               // padded rows
#define PW 124              // padded cols

#define GEOM_BLOCKS  (NPTS/256)      // 1260
#define PACKW_BLOCKS 400             // 102400 threads

typedef short s16x8 __attribute__((ext_vector_type(8)));
typedef float f32x4 __attribute__((ext_vector_type(4)));

__device__ __forceinline__ unsigned short f2bf(float f) {
    unsigned int u = __float_as_uint(f);
    unsigned int r = (u + 0x7FFFu + ((u >> 16) & 1u)) >> 16;
    return (unsigned short)r;
}

// ---------------- pad + transpose + halo-zero + counts-zero ----------------
// grid (PH, BS, 4): z = 64-channel group. 128 threads.
__global__ __launch_bounds__(128) void pad_kernel(
    const float* __restrict__ state, unsigned short* __restrict__ P,
    int* __restrict__ counts)
{
    const int h2  = blockIdx.x;      // 0..59
    const int b   = blockIdx.y;
    const int cg  = blockIdx.z;      // 0..3 (64 ch each)
    const int tid = threadIdx.x;
    unsigned short* rowp = P + (((size_t)b * PH + h2) * PW) * CIN + cg * 64;
    const int4 z4 = make_int4(0, 0, 0, 0);

    if (h2 >= 2 && h2 < 2 + HF) {
        const int h = h2 - 2;
        if (tid < WF) {
            const float* src = state + (((size_t)b * CIN + cg * 64) * HF + h) * WF + tid;
            unsigned short* dst = rowp + (size_t)(tid + 2) * CIN;
            for (int c0 = 0; c0 < 64; c0 += 8) {
                unsigned short tmp[8];
#pragma unroll
                for (int j = 0; j < 8; ++j)
                    tmp[j] = f2bf(src[(size_t)(c0 + j) * HW]);
                *(int4*)(dst + c0) = *(const int4*)tmp;
            }
        } else if (tid < 124) {
            // halo columns 0,1,122,123 (this block's 64-ch slice)
            const int w2 = (tid == 120) ? 0 : (tid == 121) ? 1 : tid;
            int4* d4 = (int4*)(rowp + (size_t)w2 * CIN);
#pragma unroll
            for (int i = 0; i < 8; ++i) d4[i] = z4;
        }
    } else {
        // full border row, this block's 64-ch slice: 124 cols x 8 int4
        for (int i = tid; i < 124 * 8; i += 128) {
            const int w2 = i >> 3, k = i & 7;
            ((int4*)(rowp + (size_t)w2 * CIN))[k] = z4;
        }
    }

    if (b == 0 && cg == 0 && h2 < 32) {
        int4* c4 = (int4*)counts;
        c4[h2 * 128 + tid] = z4;     // 32*128 int4 = 16384 ints
    }
}

// ---------------- prep: geom + weight pack + affine pack (block-range dispatch) ----------------
__global__ __launch_bounds__(256) void prep_kernel(
    const float* __restrict__ intr, const float* __restrict__ extr,
    const float* __restrict__ fw, const float* __restrict__ dw,
    const float* __restrict__ fb, const float* __restrict__ fg, const float* __restrict__ fbt,
    const float* __restrict__ db, const float* __restrict__ dg, const float* __restrict__ dbt,
    int* __restrict__ cells, int* __restrict__ counts,
    unsigned short* __restrict__ Wf, float2* __restrict__ aff)
{
    const int bid = blockIdx.x;
    const int tid = threadIdx.x;

    if (bid < GEOM_BLOCKS) {
        // ---- geometry: byte-identical numerics to the passing version ----
        int idx = bid * 256 + tid;
        int d  = idx / HW;
        int hw = idx - d * HW;
        int h  = hw / WF;
        int w  = hw - h * WF;

        float k00 = intr[0], k01 = intr[1], k02 = intr[2];
        float k11 = intr[4], k12 = intr[5];
        float k22 = intr[8];

        float A00 = __fdiv_rn(1.0f, k00);
        float A11 = __fdiv_rn(1.0f, k11);
        float A01 = __fmul_rn(__fmul_rn(k01, A00), -A11);
        float A22 = __fdiv_rn(1.0f, k22);
        float x0  = __fmul_rn(k02, A00);
        x0        = __fadd_rn(x0, __fmul_rn(k12, A01));
        float x1  = __fmul_rn(k12, A11);
        float A02 = __fmul_rn(x0, -A22);
        float A12 = __fmul_rn(x1, -A22);

        float i00 = A00, i01 = A01, i02 = A02;
        float i10 = 0.f, i11 = A11, i12 = A12;
        float i20 = 0.f, i21 = 0.f, i22 = A22;

        float u   = (w + 0.5f) * 8.0f;
        float v   = (h + 0.5f) * 8.0f;
        float dsv = 2.0f + (float)d;
        float px  = __fmul_rn(u, dsv);
        float py  = __fmul_rn(v, dsv);
        float pz  = dsv;

        float cam0 = fmaf(pz, i02, fmaf(py, i01, fmaf(px, i00, 0.0f)));
        float cam1 = fmaf(pz, i12, fmaf(py, i11, fmaf(px, i10, 0.0f)));
        float cam2 = fmaf(pz, i22, fmaf(py, i21, fmaf(px, i20, 0.0f)));

        float r00 = extr[0], r01 = extr[1], r02 = extr[2],  t0 = extr[3];
        float r10 = extr[4], r11 = extr[5], r12 = extr[6],  t1 = extr[7];

        float mm0 = fmaf(cam2, r02, fmaf(cam1, r01, fmaf(cam0, r00, 0.0f)));
        float mm1 = fmaf(cam2, r12, fmaf(cam1, r11, fmaf(cam0, r10, 0.0f)));
        float e0  = __fadd_rn(mm0, t0);
        float e1  = __fadd_rn(mm1, t1);

        float ixf = floorf(__fadd_rn(__fadd_rn(__fdiv_rn(e0, 0.6f), 32.0f), 64.0f));
        float iyf = floorf(__fadd_rn(__fdiv_rn(e1, 0.6f), 64.0f));
        int ix = (int)ixf;
        int iy = (int)iyf;

        bool valid = (ix >= 0) && (ix < BEVX) && (iy >= 0) && (iy < BEVY);
        int cell = valid ? iy * BEVX + ix : -1;
        cells[idx] = cell;
        if (valid) atomicAdd(&counts[cell], 1);
    } else if (bid < GEOM_BLOCKS + PACKW_BLOCKS) {
        // ---- weight pack ----
        int t = (bid - GEOM_BLOCKS) * 256 + tid;
        int lane = t & 63;
        int nf = (t >> 6) & 7;
        int kc = (t >> 9) & 7;
        int p  = t >> 12;
        int n   = nf * 16 + (lane & 15);
        int ci0 = kc * 32 + (lane >> 4) * 8;
        const float* src = (n < 64) ? fw + (size_t)n * CIN * 25
                                    : dw + (size_t)(n - 64) * CIN * 25;
        unsigned short v[8];
#pragma unroll
        for (int j = 0; j < 8; ++j)
            v[j] = f2bf(src[(size_t)(ci0 + j) * 25 + p]);
        *(int4*)(Wf + (size_t)t * 8) = *(const int4*)v;
    } else {
        // ---- affine pack ----
        if (tid < 128) {
            float g, bi, bt;
            if (tid < 64) { g = fg[tid]; bi = fb[tid]; bt = fbt[tid]; }
            else          { g = dg[tid - 64]; bi = db[tid - 64]; bt = dbt[tid - 64]; }
            aff[tid] = make_float2(g, g * bi + bt);
        }
    }
}

// ---------------- fused conv via MFMA implicit GEMM (+depth head in odd blocks) ----------------
// grid (15,7,BS*2): z = b*2 + nhalf. 256 threads (4 waves). Block: 64 px x 64 out-ch.
// Wave (wm, wid&1): 32 px x 32 ch. nhalf=0 -> feat (ch 0..63) -> xT.
// nhalf=1 -> dec (ch 64..127) -> LDS -> depth head (48 logits + softmax) -> dep.
__global__ __launch_bounds__(256) void conv_mfma_kernel(
    const unsigned short* __restrict__ P, const unsigned short* __restrict__ Wf,
    const float2* __restrict__ aff, const float* __restrict__ dwt,
    const float* __restrict__ dbs, float* __restrict__ xT, float* __restrict__ dep)
{
    __shared__ __align__(16) unsigned short lds[2][144 * 32];  // 18432B; reused for depth phase

    const int tid  = threadIdx.x;
    const int lane = tid & 63;
    const int wid  = tid >> 6;        // 0..3
    const int wm   = wid >> 1;        // 0..1
    const int nhalf = blockIdx.z & 1;
    const int wn_g  = (nhalf << 1) + (wid & 1);   // 0..3 global n-quarter
    const int b  = blockIdx.z >> 1;
    const int h0 = blockIdx.y * 8;
    const int w0 = blockIdx.x * 8;

    const unsigned short* Pb = P + (((size_t)b * PH + h0) * PW + w0) * CIN;

    // staging: 576 chunks of 16B (144 px x 4 slots); thread covers tid, tid+256, tid+512(<576)
    const int pix0 = tid >> 2,          slot0 = tid & 3;
    const size_t g0 = ((size_t)(pix0 / 12) * PW + (pix0 % 12)) * CIN + slot0 * 8;
    const int l0 = pix0 * 32 + (slot0 ^ ((pix0 >> 1) & 3)) * 8;
    const int c1 = 256 + tid;
    const int pix1 = c1 >> 2,           slot1 = c1 & 3;
    const size_t g1 = ((size_t)(pix1 / 12) * PW + (pix1 % 12)) * CIN + slot1 * 8;
    const int l1 = pix1 * 32 + (slot1 ^ ((pix1 >> 1) & 3)) * 8;
    const int c2 = 512 + tid;
    const int pix2 = c2 >> 2,           slot2 = c2 & 3;
    const size_t g2 = ((size_t)(pix2 / 12) * PW + (pix2 % 12)) * CIN + slot2 * 8;
    const int l2 = pix2 * 32 + (slot2 ^ ((pix2 >> 1) & 3)) * 8;
    const bool has3 = (tid < 64);

    f32x4 acc[2][2];
#pragma unroll
    for (int i = 0; i < 2; ++i)
#pragma unroll
        for (int j = 0; j < 2; ++j)
            acc[i][j] = (f32x4){0.f, 0.f, 0.f, 0.f};

    const int kg = lane >> 4;
    const int m0 = wm * 32 + (lane & 15);
    const int m1 = m0 + 16;
    const int pb0 = ((m0 >> 3)) * 12 + (m0 & 7);
    const int pb1 = ((m1 >> 3)) * 12 + (m1 & 7);

    // prologue: stage kc=0
    {
        int4 r0 = *(const int4*)(Pb + g0);
        int4 r1 = *(const int4*)(Pb + g1);
        int4 r2;
        if (has3) r2 = *(const int4*)(Pb + g2);
        *(int4*)((char*)lds[0] + (size_t)l0 * 2) = r0;
        *(int4*)((char*)lds[0] + (size_t)l1 * 2) = r1;
        if (has3) *(int4*)((char*)lds[0] + (size_t)l2 * 2) = r2;
    }
    __syncthreads();

    for (int kc = 0; kc < 8; ++kc) {
        const int cur = kc & 1;
        int4 n0, n1, n2;
        if (kc < 7) {
            n0 = *(const int4*)(Pb + g0 + (size_t)(kc + 1) * 32);
            n1 = *(const int4*)(Pb + g1 + (size_t)(kc + 1) * 32);
            if (has3) n2 = *(const int4*)(Pb + g2 + (size_t)(kc + 1) * 32);
        }
        const unsigned short* lb = lds[cur];
#pragma unroll 5
        for (int p = 0; p < 25; ++p) {
            const int poff = (p / 5) * 12 + (p % 5);
            const int px0 = pb0 + poff;
            const int px1 = pb1 + poff;
            s16x8 a0 = *(const s16x8*)(lb + px0 * 32 + (kg ^ ((px0 >> 1) & 3)) * 8);
            s16x8 a1 = *(const s16x8*)(lb + px1 * 32 + (kg ^ ((px1 >> 1) & 3)) * 8);
            const size_t we = (((size_t)(p * 8 + kc) * 8) + wn_g * 2) * 64 + lane;
            s16x8 b0 = *(const s16x8*)(Wf + we * 8);
            s16x8 b1 = *(const s16x8*)(Wf + we * 8 + 512);
            acc[0][0] = __builtin_amdgcn_mfma_f32_16x16x32_bf16(a0, b0, acc[0][0], 0, 0, 0);
            acc[1][0] = __builtin_amdgcn_mfma_f32_16x16x32_bf16(a1, b0, acc[1][0], 0, 0, 0);
            acc[0][1] = __builtin_amdgcn_mfma_f32_16x16x32_bf16(a0, b1, acc[0][1], 0, 0, 0);
            acc[1][1] = __builtin_amdgcn_mfma_f32_16x16x32_bf16(a1, b1, acc[1][1], 0, 0, 0);
        }
        if (kc < 7) {
            *(int4*)((char*)lds[cur ^ 1] + (size_t)l0 * 2) = n0;
            *(int4*)((char*)lds[cur ^ 1] + (size_t)l1 * 2) = n1;
            if (has3) *(int4*)((char*)lds[cur ^ 1] + (size_t)l2 * 2) = n2;
        }
        __syncthreads();
    }

    if (nhalf == 0) {
        // feat half -> xT (b, hw, 64ch), coalesced along ch
#pragma unroll
        for (int nf = 0; nf < 2; ++nf) {
            const int n = (wid & 1) * 32 + nf * 16 + (lane & 15);
            const float2 sc = aff[n];
#pragma unroll
            for (int mf = 0; mf < 2; ++mf) {
#pragma unroll
                for (int r = 0; r < 4; ++r) {
                    const int m = wm * 32 + mf * 16 + (lane >> 4) * 4 + r;
                    const int h = h0 + (m >> 3), w = w0 + (m & 7);
                    xT[(((size_t)b * HW) + h * WF + w) * 64 + n] =
                        fmaxf(sc.x * acc[mf][nf][r] + sc.y, 0.f);
                }
            }
        }
        return;
    }

    // ---------------- dec half -> LDS, then depth head ----------------
    float* ldsf = (float*)&lds[0][0];     // 64 px x 65 f32 = 16640B (fits 18432)
#pragma unroll
    for (int nf = 0; nf < 2; ++nf) {
        const int ch = (wid & 1) * 32 + nf * 16 + (lane & 15);
        const float2 sc = aff[64 + ch];
#pragma unroll
        for (int mf = 0; mf < 2; ++mf) {
#pragma unroll
            for (int r = 0; r < 4; ++r) {
                const int m = wm * 32 + mf * 16 + (lane >> 4) * 4 + r;
                ldsf[m * 65 + ch] = fmaxf(sc.x * acc[mf][nf][r] + sc.y, 0.f);
            }
        }
    }
    __syncthreads();

    // 48 logits + softmax: 4 waves x 12 d's, px = lane
    const int px = lane;
    const int q  = wid;
    float l[12];
#pragma unroll
    for (int j = 0; j < 12; ++j) l[j] = dbs[q * 12 + j];
    for (int c = 0; c < CF; ++c) {
        float v = ldsf[px * 65 + c];
#pragma unroll
        for (int j = 0; j < 12; ++j)
            l[j] = fmaf(v, dwt[(q * 12 + j) * CF + c], l[j]);
    }
    float pm = l[0];
#pragma unroll
    for (int j = 1; j < 12; ++j) pm = fmaxf(pm, l[j]);

    __syncthreads();
    float* red = (float*)&lds[0][0];
    red[q * 64 + px] = pm;
    __syncthreads();
    float m = fmaxf(fmaxf(red[px], red[64 + px]), fmaxf(red[128 + px], red[192 + px]));

    float ps = 0.f;
#pragma unroll
    for (int j = 0; j < 12; ++j) { l[j] = expf(l[j] - m); ps += l[j]; }
    red[256 + q * 64 + px] = ps;
    __syncthreads();
    float s = ((red[256 + px] + red[256 + 64 + px]) + red[256 + 128 + px]) + red[256 + 192 + px];
    float inv = 1.0f / s;

    const int hw = (h0 + (px >> 3)) * WF + (w0 + (px & 7));
    float* op = dep + (size_t)b * DD * HW + hw;
#pragma unroll
    for (int j = 0; j < 12; ++j)
        op[(size_t)(q * 12 + j) * HW] = l[j] * inv;
}

// ---------------- scan: 1024 threads, shfl + LDS two-level ----------------
__global__ __launch_bounds__(1024) void scan_kernel(
    const int* __restrict__ counts, int* __restrict__ offsets, int* __restrict__ cursor)
{
    __shared__ int wsum[16];
    const int tid = threadIdx.x;
    const int lane = tid & 63;
    const int wv = tid >> 6;

    int cnt[16];
    const int4* cp = (const int4*)counts;
#pragma unroll
    for (int k = 0; k < 4; ++k) {
        int4 c4 = cp[tid * 4 + k];
        cnt[k * 4 + 0] = c4.x; cnt[k * 4 + 1] = c4.y;
        cnt[k * 4 + 2] = c4.z; cnt[k * 4 + 3] = c4.w;
    }
    int s = 0;
#pragma unroll
    for (int i = 0; i < 16; ++i) s += cnt[i];

    int inc = s;
#pragma unroll
    for (int off = 1; off < 64; off <<= 1) {
        int v = __shfl_up(inc, off);
        if (lane >= off) inc += v;
    }
    if (lane == 63) wsum[wv] = inc;
    __syncthreads();
    if (tid == 0) {
        int run = 0;
#pragma unroll
        for (int i = 0; i < 16; ++i) { int v = wsum[i]; wsum[i] = run; run += v; }
        offsets[NCELL] = run;
    }
    __syncthreads();
    int run = wsum[wv] + (inc - s);
#pragma unroll
    for (int i = 0; i < 16; ++i) {
        offsets[tid * 16 + i] = run;
        cursor[tid * 16 + i]  = run;
        run += cnt[i];
    }
}

// ---------------- fill combined (point, cell) list ----------------
__global__ __launch_bounds__(256) void fill_kernel(
    const int* __restrict__ cells, int* __restrict__ cursor, int2* __restrict__ pl2)
{
    int idx = blockIdx.x * 256 + threadIdx.x;
    int c = cells[idx];
    if (c >= 0) {
        int pos = atomicAdd(&cursor[c], 1);
        int d  = idx / HW;
        int hw = idx - d * HW;
        pl2[pos] = make_int2((d << 16) | hw, c);
    }
}

// ---------------- gather2: one wave per 64-point chunk of cell-sorted list ----------------
__global__ __launch_bounds__(64) void gather2_kernel(
    const float* __restrict__ xT, const float* __restrict__ depth,
    const int2* __restrict__ pl2, const int* __restrict__ nptr,
    float* __restrict__ pooled)
{
    const int b    = blockIdx.y;
    const int lane = threadIdx.x;
    const int npts = *nptr;
    const int i0   = blockIdx.x * 64;
    if (i0 >= npts) return;
    const int n = min(64, npts - i0);

    const float* xb = xT + (size_t)b * HW * CF;
    const float* dp = depth + (size_t)b * DD * HW;
    float* pb = pooled + (size_t)b * NCELL * CF;
    const int2* q = pl2 + i0;

    float acc = 0.f;
    int cur = q[0].y;
    for (int j = 0; j < n; ++j) {
        int2 pc = q[j];                      // wave-uniform -> scalar loads
        if (pc.y != cur) {
            atomicAdd(&pb[(size_t)cur * CF + lane], acc);
            acc = 0.f;
            cur = pc.y;
        }
        int hw = pc.x & 0xFFFF;
        int d  = pc.x >> 16;
        acc = fmaf(dp[d * HW + hw], xb[(size_t)hw * CF + lane], acc);
    }
    atomicAdd(&pb[(size_t)cur * CF + lane], acc);
}

// ---------------- transpose pooled (b,cell,64) -> out (b,64,cell) ----------------
__global__ __launch_bounds__(256) void transpose_kernel(
    const float* __restrict__ pooled, float* __restrict__ out)
{
    __shared__ float t[64][65];
    const int b  = blockIdx.y;
    const int c0 = blockIdx.x * 64;
    const int tid = threadIdx.x;
#pragma unroll
    for (int k = 0; k < 16; ++k) {
        int idx = tid + k * 256;
        int cell = idx >> 6, ch = idx & 63;
        t[cell][ch] = pooled[(((size_t)b * NCELL) + c0 + cell) * CF + ch];
    }
    __syncthreads();
#pragma unroll
    for (int k = 0; k < 16; ++k) {
        int idx = tid + k * 256;
        int ch = idx >> 6, cell = idx & 63;
        out[((size_t)b * CF + ch) * NCELL + c0 + cell] = t[cell][ch];
    }
}

// ---------------- launch ----------------
extern "C" void kernel_launch(void* const* d_in, const int* in_sizes, int n_in,
                              void* d_out, int out_size, void* d_ws, size_t ws_size,
                              hipStream_t stream)
{
    const float* state   = (const float*)d_in[0];
    const float* intr    = (const float*)d_in[1];
    const float* extr    = (const float*)d_in[2];
    const float* feat_w  = (const float*)d_in[3];
    const float* feat_b  = (const float*)d_in[4];
    const float* feat_g  = (const float*)d_in[5];
    const float* feat_bt = (const float*)d_in[6];
    const float* dec_w   = (const float*)d_in[7];
    const float* dec_b   = (const float*)d_in[8];
    const float* dec_g   = (const float*)d_in[9];
    const float* dec_bt  = (const float*)d_in[10];
    const float* depth_w = (const float*)d_in[11];
    const float* depth_b = (const float*)d_in[12];
    float* out = (float*)d_out;

    // workspace carve-up (all 16B aligned)
    char* ws = (char*)d_ws;
    const size_t P_BYTES   = (size_t)BS * PH * PW * CIN * 2;       // 15,237,120
    const size_t WF_BYTES  = (size_t)25 * 8 * 8 * 64 * 16;         // 1,638,400
    const size_t AFF_BYTES = 1024;
    const size_t F_BYTES   = (size_t)BS * HW * 64 * 4;             // 6,881,280
    const size_t DEP_BYTES = (size_t)BS * DD * HW * 4;             // 5,160,960
    const size_t I_BYTES   = (size_t)NPTS * 4;                     // 1,290,240
    const size_t POOL_BYTES= (size_t)BS * NCELL * CF * 4;          // 16,777,216

    unsigned short* P   = (unsigned short*)ws;            ws += P_BYTES;
    unsigned short* Wfr = (unsigned short*)ws;            ws += WF_BYTES;
    float2*         aff = (float2*)ws;                    ws += AFF_BYTES;
    float*          xT  = (float*)ws;                     ws += F_BYTES;
    float*          dep = (float*)ws;                     ws += DEP_BYTES;
    int*            cells = (int*)ws;                     ws += I_BYTES;
    int2*           pl2   = (int2*)ws;                    ws += 2 * I_BYTES;
    int*            counts  = (int*)ws;                   ws += NCELL * 4;
    int*            offsets = (int*)ws;                   ws += (NCELL + 4) * 4;
    int*            cursor  = (int*)ws;                   ws += NCELL * 4;

    // pooled aliases P+Wf (dead after conv); 16.78MB <= 16.88MB
    float* pooled = (float*)d_ws;

    pad_kernel<<<dim3(PH, BS, 4), 128, 0, stream>>>(state, P, counts);

    prep_kernel<<<GEOM_BLOCKS + PACKW_BLOCKS + 1, 256, 0, stream>>>(
        intr, extr, feat_w, dec_w,
        feat_b, feat_g, feat_bt, dec_b, dec_g, dec_bt,
        cells, counts, Wfr, aff);

    conv_mfma_kernel<<<dim3(15, 7, BS * 2), 256, 0, stream>>>(
        P, Wfr, aff, depth_w, depth_b, xT, dep);

    scan_kernel<<<1, 1024, 0, stream>>>(counts, offsets, cursor);

    fill_kernel<<<GEOM_BLOCKS, 256, 0, stream>>>(cells, cursor, pl2);

    hipMemsetAsync(pooled, 0, POOL_BYTES, stream);

    gather2_kernel<<<dim3((NPTS + 63) / 64, BS), 64, 0, stream>>>(
        xT, dep, pl2, offsets + NCELL, pooled);

    transpose_kernel<<<dim3(NCELL / 64, BS), 256, 0, stream>>>(pooled, out);
}

// Round 9
// 295.255 us; speedup vs baseline: 10.4711x; 1.1284x over previous
//
#include <hip/hip_runtime.h>
#include <hip/hip_bf16.h>
#include <math.h>

#define BS 4
#define CIN 256
#define HF 56
#define WF 120
#define CF 64
#define DD 48
#define HW (HF*WF)          // 6720
#define BEVX 128
#define BEVY 128
#define NCELL (BEVX*BEVY)   // 16384
#define NPTS (DD*HW)        // 322560

#define PH 60               // padded rows
#define PW 124              // padded cols

#define GEOM_BLOCKS  (NPTS/256)      // 1260
#define PACKW_BLOCKS 400             // 102400 threads

typedef short s16x8 __attribute__((ext_vector_type(8)));
typedef float f32x4 __attribute__((ext_vector_type(4)));

__device__ __forceinline__ unsigned short f2bf(float f) {
    unsigned int u = __float_as_uint(f);
    unsigned int r = (u + 0x7FFFu + ((u >> 16) & 1u)) >> 16;
    return (unsigned short)r;
}
__device__ __forceinline__ float bf2f(unsigned short s) {
    return __uint_as_float(((unsigned int)s) << 16);
}

// ---------------- pad: f32 (b,ci,h,w) -> bf16 (b,h+2,w+2,ci), LDS-transposed ----------------
// grid (234, BS), 256 thr. tiles 0..209: interior 32-px tiles; 210..232: border zero; 233: counts zero.
__global__ __launch_bounds__(256) void pad_kernel(
    const float* __restrict__ state, unsigned short* __restrict__ P,
    int* __restrict__ counts)
{
    __shared__ float lt[32 * 257];
    const int tile = blockIdx.x;
    const int b    = blockIdx.y;
    const int tid  = threadIdx.x;
    const int4 z4 = make_int4(0, 0, 0, 0);

    if (tile < 210) {
        const int hw0 = tile * 32;
        const int wl = tid & 31;
        const int cg = tid >> 5;          // 0..7
        const float* src = state + (size_t)(b * CIN + cg * 32) * HW + hw0 + wl;
#pragma unroll 8
        for (int k = 0; k < 32; ++k)
            lt[wl * 257 + cg * 32 + k] = src[(size_t)k * HW];
        __syncthreads();

        const int px = tid >> 3;          // 0..31
        const int ck = tid & 7;           // 16B chunk
        const int hw = hw0 + px;
        const int h = hw / WF, w = hw - h * WF;
        unsigned short* dst = P + (((size_t)b * PH + h + 2) * PW + (w + 2)) * CIN;
#pragma unroll
        for (int r = 0; r < 4; ++r) {
            const int c0 = r * 64 + ck * 8;
            unsigned short tmp[8];
#pragma unroll
            for (int j = 0; j < 8; ++j) tmp[j] = f2bf(lt[px * 257 + c0 + j]);
            *(int4*)(dst + c0) = *(const int4*)tmp;
        }
    } else if (tile < 233) {
        // border pixels: 720 per image
        const int pxid = (tile - 210) * 32 + (tid >> 3);
        const int ck = tid & 7;
        if (pxid < 720) {
            int h2, w2;
            if (pxid < 496) { int r = pxid / 124; h2 = (r < 2) ? r : 56 + r; w2 = pxid - r * 124; }
            else { int u = pxid - 496; h2 = 2 + (u >> 2); int m = u & 3; w2 = (m < 2) ? m : 120 + m; }
            unsigned short* dst = P + (((size_t)b * PH + h2) * PW + w2) * CIN;
#pragma unroll
            for (int r = 0; r < 4; ++r)
                *(int4*)(dst + r * 64 + ck * 8) = z4;
        }
    } else {
        if (b == 0) {
            // zero ALL of counts: NCELL ints = 4096 int4 (256 thr x 16)
            int4* c4 = (int4*)counts;
#pragma unroll
            for (int r = 0; r < 16; ++r) c4[tid + r * 256] = z4;
        }
    }
}

// ---------------- prep: geom + weight pack + (aff, depth-weight frag) ----------------
__global__ __launch_bounds__(256) void prep_kernel(
    const float* __restrict__ intr, const float* __restrict__ extr,
    const float* __restrict__ fw, const float* __restrict__ dw,
    const float* __restrict__ fb, const float* __restrict__ fg, const float* __restrict__ fbt,
    const float* __restrict__ db, const float* __restrict__ dg, const float* __restrict__ dbt,
    const float* __restrict__ dpw,
    int* __restrict__ cells, int* __restrict__ counts,
    unsigned short* __restrict__ Wf, float2* __restrict__ aff,
    unsigned short* __restrict__ Wd)
{
    const int bid = blockIdx.x;
    const int tid = threadIdx.x;

    if (bid < GEOM_BLOCKS) {
        // ---- geometry: byte-identical numerics to the passing version ----
        int idx = bid * 256 + tid;
        int d  = idx / HW;
        int hw = idx - d * HW;
        int h  = hw / WF;
        int w  = hw - h * WF;

        float k00 = intr[0], k01 = intr[1], k02 = intr[2];
        float k11 = intr[4], k12 = intr[5];
        float k22 = intr[8];

        float A00 = __fdiv_rn(1.0f, k00);
        float A11 = __fdiv_rn(1.0f, k11);
        float A01 = __fmul_rn(__fmul_rn(k01, A00), -A11);
        float A22 = __fdiv_rn(1.0f, k22);
        float x0  = __fmul_rn(k02, A00);
        x0        = __fadd_rn(x0, __fmul_rn(k12, A01));
        float x1  = __fmul_rn(k12, A11);
        float A02 = __fmul_rn(x0, -A22);
        float A12 = __fmul_rn(x1, -A22);

        float i00 = A00, i01 = A01, i02 = A02;
        float i10 = 0.f, i11 = A11, i12 = A12;
        float i20 = 0.f, i21 = 0.f, i22 = A22;

        float u   = (w + 0.5f) * 8.0f;
        float v   = (h + 0.5f) * 8.0f;
        float dsv = 2.0f + (float)d;
        float px  = __fmul_rn(u, dsv);
        float py  = __fmul_rn(v, dsv);
        float pz  = dsv;

        float cam0 = fmaf(pz, i02, fmaf(py, i01, fmaf(px, i00, 0.0f)));
        float cam1 = fmaf(pz, i12, fmaf(py, i11, fmaf(px, i10, 0.0f)));
        float cam2 = fmaf(pz, i22, fmaf(py, i21, fmaf(px, i20, 0.0f)));

        float r00 = extr[0], r01 = extr[1], r02 = extr[2],  t0 = extr[3];
        float r10 = extr[4], r11 = extr[5], r12 = extr[6],  t1 = extr[7];

        float mm0 = fmaf(cam2, r02, fmaf(cam1, r01, fmaf(cam0, r00, 0.0f)));
        float mm1 = fmaf(cam2, r12, fmaf(cam1, r11, fmaf(cam0, r10, 0.0f)));
        float e0  = __fadd_rn(mm0, t0);
        float e1  = __fadd_rn(mm1, t1);

        float ixf = floorf(__fadd_rn(__fadd_rn(__fdiv_rn(e0, 0.6f), 32.0f), 64.0f));
        float iyf = floorf(__fadd_rn(__fdiv_rn(e1, 0.6f), 64.0f));
        int ix = (int)ixf;
        int iy = (int)iyf;

        bool valid = (ix >= 0) && (ix < BEVX) && (iy >= 0) && (iy < BEVY);
        int cell = valid ? iy * BEVX + ix : -1;
        cells[idx] = cell;
        if (valid) atomicAdd(&counts[cell], 1);
    } else if (bid < GEOM_BLOCKS + PACKW_BLOCKS) {
        // ---- conv weight pack ----
        int t = (bid - GEOM_BLOCKS) * 256 + tid;
        int lane = t & 63;
        int nf = (t >> 6) & 7;
        int kc = (t >> 9) & 7;
        int p  = t >> 12;
        int n   = nf * 16 + (lane & 15);
        int ci0 = kc * 32 + (lane >> 4) * 8;
        const float* src = (n < 64) ? fw + (size_t)n * CIN * 25
                                    : dw + (size_t)(n - 64) * CIN * 25;
        unsigned short v[8];
#pragma unroll
        for (int j = 0; j < 8; ++j)
            v[j] = f2bf(src[(size_t)(ci0 + j) * 25 + p]);
        *(int4*)(Wf + (size_t)t * 8) = *(const int4*)v;
    } else {
        // ---- affine pack + depth-weight B-fragments (384 entries, 256 threads) ----
        if (tid < 128) {
            float g, bi, bt;
            if (tid < 64) { g = fg[tid]; bi = fb[tid]; bt = fbt[tid]; }
            else          { g = dg[tid - 64]; bi = db[tid - 64]; bt = dbt[tid - 64]; }
            aff[tid] = make_float2(g, g * bi + bt);
        }
        for (int e = tid; e < 384; e += 256) {   // 3 n-tiles x 2 k-steps x 64 lanes
            int ln = e & 63;
            int s  = (e >> 6) & 1;
            int t  = e >> 7;
            unsigned short v[8];
#pragma unroll
            for (int j = 0; j < 8; ++j)
                v[j] = f2bf(dpw[(16 * t + (ln & 15)) * CF + s * 32 + (ln >> 4) * 8 + j]);
            *(int4*)(Wd + (size_t)e * 8) = *(const int4*)v;
        }
    }
}

// ---------------- conv (R5-proven core) via MFMA implicit GEMM, bf16 outputs ----------------
// grid (15,7,BS*2): z = b*2 + nhalf. 256 thr (4 waves). Block: 64 px x 64 out-ch.
__global__ __launch_bounds__(256) void conv_mfma_kernel(
    const unsigned short* __restrict__ P, const unsigned short* __restrict__ Wf,
    const float2* __restrict__ aff,
    unsigned short* __restrict__ xTb, unsigned short* __restrict__ decB)
{
    __shared__ __align__(16) unsigned short lds[2][144 * 32];

    const int tid  = threadIdx.x;
    const int lane = tid & 63;
    const int wid  = tid >> 6;
    const int wm   = wid >> 1;
    const int wn_g = ((blockIdx.z & 1) << 1) + (wid & 1);
    const int b  = blockIdx.z >> 1;
    const int h0 = blockIdx.y * 8;
    const int w0 = blockIdx.x * 8;

    const unsigned short* Pb = P + (((size_t)b * PH + h0) * PW + w0) * CIN;

    const int pix0 = tid >> 2,          slot0 = tid & 3;
    const size_t g0 = ((size_t)(pix0 / 12) * PW + (pix0 % 12)) * CIN + slot0 * 8;
    const int l0 = pix0 * 32 + (slot0 ^ ((pix0 >> 1) & 3)) * 8;
    const int c1 = 256 + tid;
    const int pix1 = c1 >> 2,           slot1 = c1 & 3;
    const size_t g1 = ((size_t)(pix1 / 12) * PW + (pix1 % 12)) * CIN + slot1 * 8;
    const int l1 = pix1 * 32 + (slot1 ^ ((pix1 >> 1) & 3)) * 8;
    const int c2 = 512 + tid;
    const int pix2 = c2 >> 2,           slot2 = c2 & 3;
    const size_t g2 = ((size_t)(pix2 / 12) * PW + (pix2 % 12)) * CIN + slot2 * 8;
    const int l2 = pix2 * 32 + (slot2 ^ ((pix2 >> 1) & 3)) * 8;
    const bool has3 = (tid < 64);

    f32x4 acc[2][2];
#pragma unroll
    for (int i = 0; i < 2; ++i)
#pragma unroll
        for (int j = 0; j < 2; ++j)
            acc[i][j] = (f32x4){0.f, 0.f, 0.f, 0.f};

    const int kg = lane >> 4;
    const int m0 = wm * 32 + (lane & 15);
    const int m1 = m0 + 16;
    const int pb0 = ((m0 >> 3)) * 12 + (m0 & 7);
    const int pb1 = ((m1 >> 3)) * 12 + (m1 & 7);

    {
        int4 r0 = *(const int4*)(Pb + g0);
        int4 r1 = *(const int4*)(Pb + g1);
        int4 r2;
        if (has3) r2 = *(const int4*)(Pb + g2);
        *(int4*)((char*)lds[0] + (size_t)l0 * 2) = r0;
        *(int4*)((char*)lds[0] + (size_t)l1 * 2) = r1;
        if (has3) *(int4*)((char*)lds[0] + (size_t)l2 * 2) = r2;
    }
    __syncthreads();

    for (int kc = 0; kc < 8; ++kc) {
        const int cur = kc & 1;
        int4 n0, n1, n2;
        if (kc < 7) {
            n0 = *(const int4*)(Pb + g0 + (size_t)(kc + 1) * 32);
            n1 = *(const int4*)(Pb + g1 + (size_t)(kc + 1) * 32);
            if (has3) n2 = *(const int4*)(Pb + g2 + (size_t)(kc + 1) * 32);
        }
        const unsigned short* lb = lds[cur];
#pragma unroll 5
        for (int p = 0; p < 25; ++p) {
            const int poff = (p / 5) * 12 + (p % 5);
            const int px0 = pb0 + poff;
            const int px1 = pb1 + poff;
            s16x8 a0 = *(const s16x8*)(lb + px0 * 32 + (kg ^ ((px0 >> 1) & 3)) * 8);
            s16x8 a1 = *(const s16x8*)(lb + px1 * 32 + (kg ^ ((px1 >> 1) & 3)) * 8);
            const size_t we = (((size_t)(p * 8 + kc) * 8) + wn_g * 2) * 64 + lane;
            s16x8 b0 = *(const s16x8*)(Wf + we * 8);
            s16x8 b1 = *(const s16x8*)(Wf + we * 8 + 512);
            acc[0][0] = __builtin_amdgcn_mfma_f32_16x16x32_bf16(a0, b0, acc[0][0], 0, 0, 0);
            acc[1][0] = __builtin_amdgcn_mfma_f32_16x16x32_bf16(a1, b0, acc[1][0], 0, 0, 0);
            acc[0][1] = __builtin_amdgcn_mfma_f32_16x16x32_bf16(a0, b1, acc[0][1], 0, 0, 0);
            acc[1][1] = __builtin_amdgcn_mfma_f32_16x16x32_bf16(a1, b1, acc[1][1], 0, 0, 0);
        }
        if (kc < 7) {
            *(int4*)((char*)lds[cur ^ 1] + (size_t)l0 * 2) = n0;
            *(int4*)((char*)lds[cur ^ 1] + (size_t)l1 * 2) = n1;
            if (has3) *(int4*)((char*)lds[cur ^ 1] + (size_t)l2 * 2) = n2;
        }
        __syncthreads();
    }

    // epilogue: affine + relu -> bf16, channel-last (b,hw,64)
#pragma unroll
    for (int nf = 0; nf < 2; ++nf) {
        const int n = wn_g * 32 + nf * 16 + (lane & 15);
        const float2 sc = aff[n];
        unsigned short* dst = (n < 64) ? xTb : decB;
        const int ch = n & 63;
#pragma unroll
        for (int mf = 0; mf < 2; ++mf) {
#pragma unroll
            for (int r = 0; r < 4; ++r) {
                const int m = wm * 32 + mf * 16 + (lane >> 4) * 4 + r;
                const int h = h0 + (m >> 3), w = w0 + (m & 7);
                dst[(((size_t)b * HW) + h * WF + w) * 64 + ch] =
                    f2bf(fmaxf(sc.x * acc[mf][nf][r] + sc.y, 0.f));
            }
        }
    }
}

// ---------------- depth head: MFMA 1x1 conv (64->48) + in-wave softmax ----------------
// grid 420, 256 thr (4 waves). Wave = 16 px. Output px-major: depP[px][48].
__global__ __launch_bounds__(256) void depth_kernel(
    const unsigned short* __restrict__ decB, const unsigned short* __restrict__ Wd,
    const float* __restrict__ dbs, float* __restrict__ depP)
{
    const int lane = threadIdx.x & 63;
    const int wave = blockIdx.x * 4 + (threadIdx.x >> 6);   // 0..1679
    const int px0  = wave * 16;

    const unsigned short* A = decB + (size_t)px0 * 64 + (lane & 15) * 64 + (lane >> 4) * 8;
    s16x8 a0 = *(const s16x8*)(A);
    s16x8 a1 = *(const s16x8*)(A + 32);

    f32x4 acc[3];
    float dbv[3];
#pragma unroll
    for (int t = 0; t < 3; ++t) {
        acc[t] = (f32x4){0.f, 0.f, 0.f, 0.f};
        dbv[t] = dbs[16 * t + (lane & 15)];
        s16x8 b0 = *(const s16x8*)(Wd + ((size_t)(t * 2 + 0) * 64 + lane) * 8);
        s16x8 b1 = *(const s16x8*)(Wd + ((size_t)(t * 2 + 1) * 64 + lane) * 8);
        acc[t] = __builtin_amdgcn_mfma_f32_16x16x32_bf16(a0, b0, acc[t], 0, 0, 0);
        acc[t] = __builtin_amdgcn_mfma_f32_16x16x32_bf16(a1, b1, acc[t], 0, 0, 0);
    }

#pragma unroll
    for (int r = 0; r < 4; ++r) {
        float l0 = acc[0][r] + dbv[0];
        float l1 = acc[1][r] + dbv[1];
        float l2 = acc[2][r] + dbv[2];
        float m = fmaxf(fmaxf(l0, l1), l2);
#pragma unroll
        for (int o = 1; o < 16; o <<= 1) m = fmaxf(m, __shfl_xor(m, o));
        float e0 = expf(l0 - m), e1 = expf(l1 - m), e2 = expf(l2 - m);
        float s = e0 + e1 + e2;
#pragma unroll
        for (int o = 1; o < 16; o <<= 1) s += __shfl_xor(s, o);
        float inv = 1.0f / s;
        float* op = depP + (size_t)(px0 + (lane >> 4) * 4 + r) * DD + (lane & 15);
        op[0]  = e0 * inv;
        op[16] = e1 * inv;
        op[32] = e2 * inv;
    }
}

// ---------------- scan: 1024 threads, shfl + LDS two-level ----------------
__global__ __launch_bounds__(1024) void scan_kernel(
    const int* __restrict__ counts, int* __restrict__ offsets, int* __restrict__ cursor)
{
    __shared__ int wsum[16];
    const int tid = threadIdx.x;
    const int lane = tid & 63;
    const int wv = tid >> 6;

    int cnt[16];
    const int4* cp = (const int4*)counts;
#pragma unroll
    for (int k = 0; k < 4; ++k) {
        int4 c4 = cp[tid * 4 + k];
        cnt[k * 4 + 0] = c4.x; cnt[k * 4 + 1] = c4.y;
        cnt[k * 4 + 2] = c4.z; cnt[k * 4 + 3] = c4.w;
    }
    int s = 0;
#pragma unroll
    for (int i = 0; i < 16; ++i) s += cnt[i];

    int inc = s;
#pragma unroll
    for (int off = 1; off < 64; off <<= 1) {
        int v = __shfl_up(inc, off);
        if (lane >= off) inc += v;
    }
    if (lane == 63) wsum[wv] = inc;
    __syncthreads();
    if (tid == 0) {
        int run = 0;
#pragma unroll
        for (int i = 0; i < 16; ++i) { int v = wsum[i]; wsum[i] = run; run += v; }
        offsets[NCELL] = run;
    }
    __syncthreads();
    int run = wsum[wv] + (inc - s);
#pragma unroll
    for (int i = 0; i < 16; ++i) {
        offsets[tid * 16 + i] = run;
        cursor[tid * 16 + i]  = run;
        run += cnt[i];
    }
}

// ---------------- fill combined (point,cell) list + zero pooled ----------------
__global__ __launch_bounds__(256) void fill_kernel(
    const int* __restrict__ cells, int* __restrict__ cursor, int2* __restrict__ pl2,
    float4* __restrict__ poolz)
{
    const int gid = blockIdx.x * 256 + threadIdx.x;
    // zero pooled: BS*NCELL*CF floats = 1048576 float4
    const float4 z = make_float4(0.f, 0.f, 0.f, 0.f);
#pragma unroll
    for (int r = 0; r < 4; ++r) {
        int i = gid + r * (GEOM_BLOCKS * 256);
        if (i < (BS * NCELL * CF) / 4) poolz[i] = z;
    }
    int c = cells[gid];
    if (c >= 0) {
        int pos = atomicAdd(&cursor[c], 1);
        int d  = gid / HW;
        int hw = gid - d * HW;
        pl2[pos] = make_int2((d << 16) | hw, c);
    }
}

// ---------------- gather2: one wave per 64-point chunk; lane-preload + shfl ----------------
__global__ __launch_bounds__(64) void gather2_kernel(
    const unsigned short* __restrict__ xTb, const float* __restrict__ depP,
    const int2* __restrict__ pl2, const int* __restrict__ nptr,
    float* __restrict__ pooled)
{
    const int b    = blockIdx.y;
    const int lane = threadIdx.x;
    const int npts = *nptr;
    const int i0   = blockIdx.x * 64;
    if (i0 >= npts) return;
    const int n = min(64, npts - i0);

    const unsigned short* xb = xTb + (size_t)b * HW * CF;
    const float* dp = depP + (size_t)b * HW * DD;
    float* pb = pooled + (size_t)b * NCELL * CF;

    int2 pc = make_int2(0, -1);
    float dv = 0.f;
    if (i0 + lane < npts) {
        pc = pl2[i0 + lane];
        int hw = pc.x & 0xFFFF, d = pc.x >> 16;
        dv = dp[(size_t)hw * DD + d];
    }

    float acc = 0.f;
    int cur = __shfl(pc.y, 0);
    for (int j = 0; j < n; ++j) {
        int px = __shfl(pc.x, j);
        int c  = __shfl(pc.y, j);
        float w = __shfl(dv, j);
        if (c != cur) {
            atomicAdd(&pb[(size_t)cur * CF + lane], acc);
            acc = 0.f;
            cur = c;
        }
        int hw = px & 0xFFFF;
        acc = fmaf(w, bf2f(xb[(size_t)hw * CF + lane]), acc);
    }
    atomicAdd(&pb[(size_t)cur * CF + lane], acc);
}

// ---------------- transpose pooled (b,cell,64) -> out (b,64,cell) ----------------
__global__ __launch_bounds__(256) void transpose_kernel(
    const float* __restrict__ pooled, float* __restrict__ out)
{
    __shared__ float t[64][65];
    const int b  = blockIdx.y;
    const int c0 = blockIdx.x * 64;
    const int tid = threadIdx.x;
#pragma unroll
    for (int k = 0; k < 16; ++k) {
        int idx = tid + k * 256;
        int cell = idx >> 6, ch = idx & 63;
        t[cell][ch] = pooled[(((size_t)b * NCELL) + c0 + cell) * CF + ch];
    }
    __syncthreads();
#pragma unroll
    for (int k = 0; k < 16; ++k) {
        int idx = tid + k * 256;
        int ch = idx >> 6, cell = idx & 63;
        out[((size_t)b * CF + ch) * NCELL + c0 + cell] = t[cell][ch];
    }
}

// ---------------- launch ----------------
extern "C" void kernel_launch(void* const* d_in, const int* in_sizes, int n_in,
                              void* d_out, int out_size, void* d_ws, size_t ws_size,
                              hipStream_t stream)
{
    const float* state   = (const float*)d_in[0];
    const float* intr    = (const float*)d_in[1];
    const float* extr    = (const float*)d_in[2];
    const float* feat_w  = (const float*)d_in[3];
    const float* feat_b  = (const float*)d_in[4];
    const float* feat_g  = (const float*)d_in[5];
    const float* feat_bt = (const float*)d_in[6];
    const float* dec_w   = (const float*)d_in[7];
    const float* dec_b   = (const float*)d_in[8];
    const float* dec_g   = (const float*)d_in[9];
    const float* dec_bt  = (const float*)d_in[10];
    const float* depth_w = (const float*)d_in[11];
    const float* depth_b = (const float*)d_in[12];
    float* out = (float*)d_out;

    // workspace carve-up (pooled aliases P+Wf, both dead after conv)
    char* ws = (char*)d_ws;
    const size_t P_BYTES   = (size_t)BS * PH * PW * CIN * 2;   // 15,237,120
    const size_t WF_BYTES  = (size_t)25 * 8 * 8 * 64 * 16;     // 1,638,400
    const size_t AFF_BYTES = 1024;
    const size_t WD_BYTES  = 384 * 16;                         // 6,144
    const size_t FB_BYTES  = (size_t)BS * HW * CF * 2;         // 3,440,640 (bf16)
    const size_t DEP_BYTES = (size_t)BS * HW * DD * 4;         // 5,160,960
    const size_t I_BYTES   = (size_t)NPTS * 4;

    unsigned short* P    = (unsigned short*)ws;           ws += P_BYTES;
    unsigned short* Wfr  = (unsigned short*)ws;           ws += WF_BYTES;
    float2*         aff  = (float2*)ws;                   ws += AFF_BYTES;
    unsigned short* Wd   = (unsigned short*)ws;           ws += WD_BYTES;
    unsigned short* xTb  = (unsigned short*)ws;           ws += FB_BYTES;
    unsigned short* decB = (unsigned short*)ws;           ws += FB_BYTES;
    float*          depP = (float*)ws;                    ws += DEP_BYTES;
    int*            cells = (int*)ws;                     ws += I_BYTES;
    int2*           pl2   = (int2*)ws;                    ws += 2 * I_BYTES;
    int*            counts  = (int*)ws;                   ws += NCELL * 4;
    int*            offsets = (int*)ws;                   ws += (NCELL + 4) * 4;
    int*            cursor  = (int*)ws;                   ws += NCELL * 4;

    float* pooled = (float*)d_ws;   // 16.78MB, inside P+Wf (16.88MB)

    pad_kernel<<<dim3(234, BS), 256, 0, stream>>>(state, P, counts);

    prep_kernel<<<GEOM_BLOCKS + PACKW_BLOCKS + 1, 256, 0, stream>>>(
        intr, extr, feat_w, dec_w,
        feat_b, feat_g, feat_bt, dec_b, dec_g, dec_bt, depth_w,
        cells, counts, Wfr, aff, Wd);

    scan_kernel<<<1, 1024, 0, stream>>>(counts, offsets, cursor);

    conv_mfma_kernel<<<dim3(15, 7, BS * 2), 256, 0, stream>>>(
        P, Wfr, aff, xTb, decB);

    depth_kernel<<<420, 256, 0, stream>>>(decB, Wd, depth_b, depP);

    fill_kernel<<<GEOM_BLOCKS, 256, 0, stream>>>(cells, cursor, pl2, (float4*)pooled);

    gather2_kernel<<<dim3(NPTS / 64, BS), 64, 0, stream>>>(
        xTb, depP, pl2, offsets + NCELL, pooled);

    transpose_kernel<<<dim3(NCELL / 64, BS), 256, 0, stream>>>(pooled, out);
}

// Round 10
// 189.721 us; speedup vs baseline: 16.2958x; 1.5563x over previous
//
#include <hip/hip_runtime.h>
#include <hip/hip_bf16.h>
#include <math.h>

#define BS 4
#define CIN 256
#define HF 56
#define WF 120
#define CF 64
#define DD 48
#define HW (HF*WF)          // 6720
#define BEVX 128
#define BEVY 128
#define NCELL (BEVX*BEVY)   // 16384
#define NPTS (DD*HW)        // 322560

#define PH 60               // padded rows
#define PW 124              // padded cols

#define PACKW_BLOCKS 400             // 102400 threads
#define CELL_BLOCKS  23              // 5760 (w,d) pairs / 256

typedef short s16x8 __attribute__((ext_vector_type(8)));
typedef float f32x4 __attribute__((ext_vector_type(4)));

__device__ __forceinline__ unsigned short f2bf(float f) {
    unsigned int u = __float_as_uint(f);
    unsigned int r = (u + 0x7FFFu + ((u >> 16) & 1u)) >> 16;
    return (unsigned short)r;
}
__device__ __forceinline__ float bf2f(unsigned short s) {
    return __uint_as_float(((unsigned int)s) << 16);
}

// ---------------- pad: f32 (b,ci,h,w) -> bf16 (b,h+2,w+2,ci), LDS-transposed ----------------
__global__ __launch_bounds__(256) void pad_kernel(
    const float* __restrict__ state, unsigned short* __restrict__ P)
{
    __shared__ float lt[32 * 257];
    const int tile = blockIdx.x;
    const int b    = blockIdx.y;
    const int tid  = threadIdx.x;
    const int4 z4 = make_int4(0, 0, 0, 0);

    if (tile < 210) {
        const int hw0 = tile * 32;
        const int wl = tid & 31;
        const int cg = tid >> 5;          // 0..7
        const float* src = state + (size_t)(b * CIN + cg * 32) * HW + hw0 + wl;
#pragma unroll 8
        for (int k = 0; k < 32; ++k)
            lt[wl * 257 + cg * 32 + k] = src[(size_t)k * HW];
        __syncthreads();

        const int px = tid >> 3;          // 0..31
        const int ck = tid & 7;           // 16B chunk
        const int hw = hw0 + px;
        const int h = hw / WF, w = hw - h * WF;
        unsigned short* dst = P + (((size_t)b * PH + h + 2) * PW + (w + 2)) * CIN;
#pragma unroll
        for (int r = 0; r < 4; ++r) {
            const int c0 = r * 64 + ck * 8;
            unsigned short tmp[8];
#pragma unroll
            for (int j = 0; j < 8; ++j) tmp[j] = f2bf(lt[px * 257 + c0 + j]);
            *(int4*)(dst + c0) = *(const int4*)tmp;
        }
    } else {
        // border pixels: 720 per image
        const int pxid = (tile - 210) * 32 + (tid >> 3);
        const int ck = tid & 7;
        if (pxid < 720) {
            int h2, w2;
            if (pxid < 496) { int r = pxid / 124; h2 = (r < 2) ? r : 56 + r; w2 = pxid - r * 124; }
            else { int u = pxid - 496; h2 = 2 + (u >> 2); int m = u & 3; w2 = (m < 2) ? m : 120 + m; }
            unsigned short* dst = P + (((size_t)b * PH + h2) * PW + w2) * CIN;
#pragma unroll
            for (int r = 0; r < 4; ++r)
                *(int4*)(dst + r * 64 + ck * 8) = z4;
        }
    }
}

// ---------------- prep: weight pack + aff/Wd + cell table ----------------
// bid < 400: conv weight pack. bid == 400: aff + depth-weight frags.
// bid 401..423: celltab[(d,w)] via the byte-exact geometry (h-independent).
__global__ __launch_bounds__(256) void prep_kernel(
    const float* __restrict__ intr, const float* __restrict__ extr,
    const float* __restrict__ fw, const float* __restrict__ dw,
    const float* __restrict__ fb, const float* __restrict__ fg, const float* __restrict__ fbt,
    const float* __restrict__ db, const float* __restrict__ dg, const float* __restrict__ dbt,
    const float* __restrict__ dpw,
    unsigned short* __restrict__ Wf, float2* __restrict__ aff,
    unsigned short* __restrict__ Wd, int* __restrict__ celltab)
{
    const int bid = blockIdx.x;
    const int tid = threadIdx.x;

    if (bid < PACKW_BLOCKS) {
        // ---- conv weight pack ----
        int t = bid * 256 + tid;
        int lane = t & 63;
        int nf = (t >> 6) & 7;
        int kc = (t >> 9) & 7;
        int p  = t >> 12;
        int n   = nf * 16 + (lane & 15);
        int ci0 = kc * 32 + (lane >> 4) * 8;
        const float* src = (n < 64) ? fw + (size_t)n * CIN * 25
                                    : dw + (size_t)(n - 64) * CIN * 25;
        unsigned short v[8];
#pragma unroll
        for (int j = 0; j < 8; ++j)
            v[j] = f2bf(src[(size_t)(ci0 + j) * 25 + p]);
        *(int4*)(Wf + (size_t)t * 8) = *(const int4*)v;
    } else if (bid == PACKW_BLOCKS) {
        // ---- affine pack + depth-weight B-fragments ----
        if (tid < 128) {
            float g, bi, bt;
            if (tid < 64) { g = fg[tid]; bi = fb[tid]; bt = fbt[tid]; }
            else          { g = dg[tid - 64]; bi = db[tid - 64]; bt = dbt[tid - 64]; }
            aff[tid] = make_float2(g, g * bi + bt);
        }
        for (int e = tid; e < 384; e += 256) {
            int ln = e & 63;
            int s  = (e >> 6) & 1;
            int t  = e >> 7;
            unsigned short v[8];
#pragma unroll
            for (int j = 0; j < 8; ++j)
                v[j] = f2bf(dpw[(16 * t + (ln & 15)) * CF + s * 32 + (ln >> 4) * 8 + j]);
            *(int4*)(Wd + (size_t)e * 8) = *(const int4*)v;
        }
    } else {
        // ---- cell table: byte-identical geometry numerics, evaluated per (d,w) ----
        int pair = (bid - PACKW_BLOCKS - 1) * 256 + tid;
        if (pair >= DD * WF) return;
        int d = pair / WF;
        int w = pair - d * WF;
        int h = 0;                        // geometry is bit-exactly h-independent

        float k00 = intr[0], k01 = intr[1], k02 = intr[2];
        float k11 = intr[4], k12 = intr[5];
        float k22 = intr[8];

        float A00 = __fdiv_rn(1.0f, k00);
        float A11 = __fdiv_rn(1.0f, k11);
        float A01 = __fmul_rn(__fmul_rn(k01, A00), -A11);
        float A22 = __fdiv_rn(1.0f, k22);
        float x0  = __fmul_rn(k02, A00);
        x0        = __fadd_rn(x0, __fmul_rn(k12, A01));
        float x1  = __fmul_rn(k12, A11);
        float A02 = __fmul_rn(x0, -A22);
        float A12 = __fmul_rn(x1, -A22);

        float i00 = A00, i01 = A01, i02 = A02;
        float i10 = 0.f, i11 = A11, i12 = A12;
        float i20 = 0.f, i21 = 0.f, i22 = A22;

        float u   = (w + 0.5f) * 8.0f;
        float v   = (h + 0.5f) * 8.0f;
        float dsv = 2.0f + (float)d;
        float px  = __fmul_rn(u, dsv);
        float py  = __fmul_rn(v, dsv);
        float pz  = dsv;

        float cam0 = fmaf(pz, i02, fmaf(py, i01, fmaf(px, i00, 0.0f)));
        float cam1 = fmaf(pz, i12, fmaf(py, i11, fmaf(px, i10, 0.0f)));
        float cam2 = fmaf(pz, i22, fmaf(py, i21, fmaf(px, i20, 0.0f)));

        float r00 = extr[0], r01 = extr[1], r02 = extr[2],  t0 = extr[3];
        float r10 = extr[4], r11 = extr[5], r12 = extr[6],  t1 = extr[7];

        float mm0 = fmaf(cam2, r02, fmaf(cam1, r01, fmaf(cam0, r00, 0.0f)));
        float mm1 = fmaf(cam2, r12, fmaf(cam1, r11, fmaf(cam0, r10, 0.0f)));
        float e0  = __fadd_rn(mm0, t0);
        float e1  = __fadd_rn(mm1, t1);

        float ixf = floorf(__fadd_rn(__fadd_rn(__fdiv_rn(e0, 0.6f), 32.0f), 64.0f));
        float iyf = floorf(__fadd_rn(__fdiv_rn(e1, 0.6f), 64.0f));
        int ix = (int)ixf;
        int iy = (int)iyf;

        bool valid = (ix >= 0) && (ix < BEVX) && (iy >= 0) && (iy < BEVY);
        celltab[pair] = valid ? iy * BEVX + ix : -1;
    }
}

// ---------------- conv (R5-proven core) via MFMA implicit GEMM, bf16 outputs ----------------
__global__ __launch_bounds__(256) void conv_mfma_kernel(
    const unsigned short* __restrict__ P, const unsigned short* __restrict__ Wf,
    const float2* __restrict__ aff,
    unsigned short* __restrict__ xTb, unsigned short* __restrict__ decB)
{
    __shared__ __align__(16) unsigned short lds[2][144 * 32];

    const int tid  = threadIdx.x;
    const int lane = tid & 63;
    const int wid  = tid >> 6;
    const int wm   = wid >> 1;
    const int wn_g = ((blockIdx.z & 1) << 1) + (wid & 1);
    const int b  = blockIdx.z >> 1;
    const int h0 = blockIdx.y * 8;
    const int w0 = blockIdx.x * 8;

    const unsigned short* Pb = P + (((size_t)b * PH + h0) * PW + w0) * CIN;

    const int pix0 = tid >> 2,          slot0 = tid & 3;
    const size_t g0 = ((size_t)(pix0 / 12) * PW + (pix0 % 12)) * CIN + slot0 * 8;
    const int l0 = pix0 * 32 + (slot0 ^ ((pix0 >> 1) & 3)) * 8;
    const int c1 = 256 + tid;
    const int pix1 = c1 >> 2,           slot1 = c1 & 3;
    const size_t g1 = ((size_t)(pix1 / 12) * PW + (pix1 % 12)) * CIN + slot1 * 8;
    const int l1 = pix1 * 32 + (slot1 ^ ((pix1 >> 1) & 3)) * 8;
    const int c2 = 512 + tid;
    const int pix2 = c2 >> 2,           slot2 = c2 & 3;
    const size_t g2 = ((size_t)(pix2 / 12) * PW + (pix2 % 12)) * CIN + slot2 * 8;
    const int l2 = pix2 * 32 + (slot2 ^ ((pix2 >> 1) & 3)) * 8;
    const bool has3 = (tid < 64);

    f32x4 acc[2][2];
#pragma unroll
    for (int i = 0; i < 2; ++i)
#pragma unroll
        for (int j = 0; j < 2; ++j)
            acc[i][j] = (f32x4){0.f, 0.f, 0.f, 0.f};

    const int kg = lane >> 4;
    const int m0 = wm * 32 + (lane & 15);
    const int m1 = m0 + 16;
    const int pb0 = ((m0 >> 3)) * 12 + (m0 & 7);
    const int pb1 = ((m1 >> 3)) * 12 + (m1 & 7);

    {
        int4 r0 = *(const int4*)(Pb + g0);
        int4 r1 = *(const int4*)(Pb + g1);
        int4 r2;
        if (has3) r2 = *(const int4*)(Pb + g2);
        *(int4*)((char*)lds[0] + (size_t)l0 * 2) = r0;
        *(int4*)((char*)lds[0] + (size_t)l1 * 2) = r1;
        if (has3) *(int4*)((char*)lds[0] + (size_t)l2 * 2) = r2;
    }
    __syncthreads();

    for (int kc = 0; kc < 8; ++kc) {
        const int cur = kc & 1;
        int4 n0, n1, n2;
        if (kc < 7) {
            n0 = *(const int4*)(Pb + g0 + (size_t)(kc + 1) * 32);
            n1 = *(const int4*)(Pb + g1 + (size_t)(kc + 1) * 32);
            if (has3) n2 = *(const int4*)(Pb + g2 + (size_t)(kc + 1) * 32);
        }
        const unsigned short* lb = lds[cur];
#pragma unroll 5
        for (int p = 0; p < 25; ++p) {
            const int poff = (p / 5) * 12 + (p % 5);
            const int px0 = pb0 + poff;
            const int px1 = pb1 + poff;
            s16x8 a0 = *(const s16x8*)(lb + px0 * 32 + (kg ^ ((px0 >> 1) & 3)) * 8);
            s16x8 a1 = *(const s16x8*)(lb + px1 * 32 + (kg ^ ((px1 >> 1) & 3)) * 8);
            const size_t we = (((size_t)(p * 8 + kc) * 8) + wn_g * 2) * 64 + lane;
            s16x8 b0 = *(const s16x8*)(Wf + we * 8);
            s16x8 b1 = *(const s16x8*)(Wf + we * 8 + 512);
            acc[0][0] = __builtin_amdgcn_mfma_f32_16x16x32_bf16(a0, b0, acc[0][0], 0, 0, 0);
            acc[1][0] = __builtin_amdgcn_mfma_f32_16x16x32_bf16(a1, b0, acc[1][0], 0, 0, 0);
            acc[0][1] = __builtin_amdgcn_mfma_f32_16x16x32_bf16(a0, b1, acc[0][1], 0, 0, 0);
            acc[1][1] = __builtin_amdgcn_mfma_f32_16x16x32_bf16(a1, b1, acc[1][1], 0, 0, 0);
        }
        if (kc < 7) {
            *(int4*)((char*)lds[cur ^ 1] + (size_t)l0 * 2) = n0;
            *(int4*)((char*)lds[cur ^ 1] + (size_t)l1 * 2) = n1;
            if (has3) *(int4*)((char*)lds[cur ^ 1] + (size_t)l2 * 2) = n2;
        }
        __syncthreads();
    }

    // epilogue: affine + relu -> bf16, channel-last (b,hw,64)
#pragma unroll
    for (int nf = 0; nf < 2; ++nf) {
        const int n = wn_g * 32 + nf * 16 + (lane & 15);
        const float2 sc = aff[n];
        unsigned short* dst = (n < 64) ? xTb : decB;
        const int ch = n & 63;
#pragma unroll
        for (int mf = 0; mf < 2; ++mf) {
#pragma unroll
            for (int r = 0; r < 4; ++r) {
                const int m = wm * 32 + mf * 16 + (lane >> 4) * 4 + r;
                const int h = h0 + (m >> 3), w = w0 + (m & 7);
                dst[(((size_t)b * HW) + h * WF + w) * 64 + ch] =
                    f2bf(fmaxf(sc.x * acc[mf][nf][r] + sc.y, 0.f));
            }
        }
    }
}

// ---------------- depth head: MFMA 1x1 conv (64->48) + in-wave softmax + pooled zero ----------------
// grid 420, 256 thr (4 waves). Wave = 16 px. Output px-major: depP[px][48].
__global__ __launch_bounds__(256) void depth_kernel(
    const unsigned short* __restrict__ decB, const unsigned short* __restrict__ Wd,
    const float* __restrict__ dbs, float* __restrict__ depP, float4* __restrict__ poolz)
{
    // zero pooled: BS*NCELL*CF floats = 1048576 float4 over 420*256 threads
    {
        const int gid = blockIdx.x * 256 + threadIdx.x;
        const float4 z = make_float4(0.f, 0.f, 0.f, 0.f);
#pragma unroll
        for (int r = 0; r < 10; ++r) {
            int i = gid + r * (420 * 256);
            if (i < (BS * NCELL * CF) / 4) poolz[i] = z;
        }
    }

    const int lane = threadIdx.x & 63;
    const int wave = blockIdx.x * 4 + (threadIdx.x >> 6);   // 0..1679
    const int px0  = wave * 16;

    const unsigned short* A = decB + (size_t)px0 * 64 + (lane & 15) * 64 + (lane >> 4) * 8;
    s16x8 a0 = *(const s16x8*)(A);
    s16x8 a1 = *(const s16x8*)(A + 32);

    f32x4 acc[3];
    float dbv[3];
#pragma unroll
    for (int t = 0; t < 3; ++t) {
        acc[t] = (f32x4){0.f, 0.f, 0.f, 0.f};
        dbv[t] = dbs[16 * t + (lane & 15)];
        s16x8 b0 = *(const s16x8*)(Wd + ((size_t)(t * 2 + 0) * 64 + lane) * 8);
        s16x8 b1 = *(const s16x8*)(Wd + ((size_t)(t * 2 + 1) * 64 + lane) * 8);
        acc[t] = __builtin_amdgcn_mfma_f32_16x16x32_bf16(a0, b0, acc[t], 0, 0, 0);
        acc[t] = __builtin_amdgcn_mfma_f32_16x16x32_bf16(a1, b1, acc[t], 0, 0, 0);
    }

#pragma unroll
    for (int r = 0; r < 4; ++r) {
        float l0 = acc[0][r] + dbv[0];
        float l1 = acc[1][r] + dbv[1];
        float l2 = acc[2][r] + dbv[2];
        float m = fmaxf(fmaxf(l0, l1), l2);
#pragma unroll
        for (int o = 1; o < 16; o <<= 1) m = fmaxf(m, __shfl_xor(m, o));
        float e0 = expf(l0 - m), e1 = expf(l1 - m), e2 = expf(l2 - m);
        float s = e0 + e1 + e2;
#pragma unroll
        for (int o = 1; o < 16; o <<= 1) s += __shfl_xor(s, o);
        float inv = 1.0f / s;
        float* op = depP + (size_t)(px0 + (lane >> 4) * 4 + r) * DD + (lane & 15);
        op[0]  = e0 * inv;
        op[16] = e1 * inv;
        op[32] = e2 * inv;
    }
}

// ---------------- colsum: dense h-reduction per (w,d), scatter per cell ----------------
// grid (WF, 3, BS). 256 thr = 4 waves; wave wv owns d = y*16 + wv*4 .. +3. lanes = channels.
__global__ __launch_bounds__(256) void colsum_kernel(
    const unsigned short* __restrict__ xTb, const float* __restrict__ depP,
    const int* __restrict__ celltab, float* __restrict__ pooled)
{
    const int w  = blockIdx.x;
    const int b  = blockIdx.z;
    const int lane = threadIdx.x & 63;
    const int wv   = threadIdx.x >> 6;
    const int dbase = blockIdx.y * 16 + wv * 4;

    int cells[4];
    bool anyv = false;
#pragma unroll
    for (int j = 0; j < 4; ++j) {
        cells[j] = celltab[(dbase + j) * WF + w];
        anyv |= (cells[j] >= 0);
    }
    if (!anyv) return;

    const unsigned short* xp = xTb + (((size_t)b * HW) + w) * 64 + lane;
    const float* dp = depP + (((size_t)b * HW) + w) * DD + dbase;

    float acc[4] = {0.f, 0.f, 0.f, 0.f};
#pragma unroll 8
    for (int h = 0; h < HF; ++h) {
        float xv = bf2f(xp[(size_t)h * WF * 64]);
        float4 dv = *(const float4*)(dp + (size_t)h * WF * DD);
        acc[0] = fmaf(dv.x, xv, acc[0]);
        acc[1] = fmaf(dv.y, xv, acc[1]);
        acc[2] = fmaf(dv.z, xv, acc[2]);
        acc[3] = fmaf(dv.w, xv, acc[3]);
    }

    float* pb = pooled + (size_t)b * NCELL * CF;
#pragma unroll
    for (int j = 0; j < 4; ++j)
        if (cells[j] >= 0)
            atomicAdd(&pb[(size_t)cells[j] * CF + lane], acc[j]);
}

// ---------------- transpose pooled (b,cell,64) -> out (b,64,cell) ----------------
__global__ __launch_bounds__(256) void transpose_kernel(
    const float* __restrict__ pooled, float* __restrict__ out)
{
    __shared__ float t[64][65];
    const int b  = blockIdx.y;
    const int c0 = blockIdx.x * 64;
    const int tid = threadIdx.x;
#pragma unroll
    for (int k = 0; k < 16; ++k) {
        int idx = tid + k * 256;
        int cell = idx >> 6, ch = idx & 63;
        t[cell][ch] = pooled[(((size_t)b * NCELL) + c0 + cell) * CF + ch];
    }
    __syncthreads();
#pragma unroll
    for (int k = 0; k < 16; ++k) {
        int idx = tid + k * 256;
        int ch = idx >> 6, cell = idx & 63;
        out[((size_t)b * CF + ch) * NCELL + c0 + cell] = t[cell][ch];
    }
}

// ---------------- launch ----------------
extern "C" void kernel_launch(void* const* d_in, const int* in_sizes, int n_in,
                              void* d_out, int out_size, void* d_ws, size_t ws_size,
                              hipStream_t stream)
{
    const float* state   = (const float*)d_in[0];
    const float* intr    = (const float*)d_in[1];
    const float* extr    = (const float*)d_in[2];
    const float* feat_w  = (const float*)d_in[3];
    const float* feat_b  = (const float*)d_in[4];
    const float* feat_g  = (const float*)d_in[5];
    const float* feat_bt = (const float*)d_in[6];
    const float* dec_w   = (const float*)d_in[7];
    const float* dec_b   = (const float*)d_in[8];
    const float* dec_g   = (const float*)d_in[9];
    const float* dec_bt  = (const float*)d_in[10];
    const float* depth_w = (const float*)d_in[11];
    const float* depth_b = (const float*)d_in[12];
    float* out = (float*)d_out;

    // workspace carve-up (pooled aliases P+Wf, dead after conv)
    char* ws = (char*)d_ws;
    const size_t P_BYTES   = (size_t)BS * PH * PW * CIN * 2;   // 15,237,120
    const size_t WF_BYTES  = (size_t)25 * 8 * 8 * 64 * 16;     // 1,638,400
    const size_t AFF_BYTES = 1024;
    const size_t WD_BYTES  = 384 * 16;                         // 6,144
    const size_t FB_BYTES  = (size_t)BS * HW * CF * 2;         // 3,440,640 (bf16)
    const size_t DEP_BYTES = (size_t)BS * HW * DD * 4;         // 5,160,960
    const size_t CT_BYTES  = ((size_t)DD * WF + 64) * 4;       // cell table

    unsigned short* P    = (unsigned short*)ws;           ws += P_BYTES;
    unsigned short* Wfr  = (unsigned short*)ws;           ws += WF_BYTES;
    float2*         aff  = (float2*)ws;                   ws += AFF_BYTES;
    unsigned short* Wd   = (unsigned short*)ws;           ws += WD_BYTES;
    unsigned short* xTb  = (unsigned short*)ws;           ws += FB_BYTES;
    unsigned short* decB = (unsigned short*)ws;           ws += FB_BYTES;
    float*          depP = (float*)ws;                    ws += DEP_BYTES;
    int*            celltab = (int*)ws;                   ws += CT_BYTES;

    float* pooled = (float*)d_ws;   // 16.78MB, inside P+Wf (16.88MB)

    pad_kernel<<<dim3(233, BS), 256, 0, stream>>>(state, P);

    prep_kernel<<<PACKW_BLOCKS + 1 + CELL_BLOCKS, 256, 0, stream>>>(
        intr, extr, feat_w, dec_w,
        feat_b, feat_g, feat_bt, dec_b, dec_g, dec_bt, depth_w,
        Wfr, aff, Wd, celltab);

    conv_mfma_kernel<<<dim3(15, 7, BS * 2), 256, 0, stream>>>(
        P, Wfr, aff, xTb, decB);

    depth_kernel<<<420, 256, 0, stream>>>(decB, Wd, depth_b, depP, (float4*)pooled);

    colsum_kernel<<<dim3(WF, 3, BS), 256, 0, stream>>>(xTb, depP, celltab, pooled);

    transpose_kernel<<<dim3(NCELL / 64, BS), 256, 0, stream>>>(pooled, out);
}